// Round 9
// baseline (1184.932 us; speedup 1.0000x reference)
//
#include <hip/hip_runtime.h>
#include <hip/hip_bf16.h>
#include <stdint.h>

#define B_  32
#define L_  2048   // L1 == L2
#define D_  1024   // D1 == D2

typedef __attribute__((ext_vector_type(8))) _Float16 f16x8;
typedef __attribute__((ext_vector_type(4))) float f32x4;
typedef __attribute__((ext_vector_type(16))) float f32x16;

// ---------- helpers ----------
__device__ __forceinline__ unsigned enc_f(float x) {
  unsigned u = __float_as_uint(x);
  return (u & 0x80000000u) ? ~u : (u | 0x80000000u);
}
__device__ __forceinline__ float dec_f(unsigned e) {
  unsigned u = (e & 0x80000000u) ? (e ^ 0x80000000u) : ~e;
  return __uint_as_float(u);
}
__device__ __forceinline__ ushort f16_bits(float x) {
  _Float16 h = (_Float16)x;               // RNE convert
  return __builtin_bit_cast(ushort, h);
}
__device__ __forceinline__ void split_f16(float x, ushort& h, ushort& l) {
  _Float16 hf = (_Float16)x;
  float r = x - (float)hf;
  h = __builtin_bit_cast(ushort, hf);
  l = __builtin_bit_cast(ushort, (_Float16)r);
}

// async global->LDS, 16B per lane; LDS dest wave-uniform, lane*16 placement.
__device__ __forceinline__ void gl_lds16(const ushort* g, ushort* l) {
  using gas_t = const __attribute__((address_space(1))) uint32_t*;
  using las_t = __attribute__((address_space(3))) uint32_t*;
  __builtin_amdgcn_global_load_lds((gas_t)(uintptr_t)g,
                                   (las_t)(unsigned)(uintptr_t)l, 16, 0, 0);
}

// ---------- decompose fp32 -> f16 hi plane only (for x1) ----------
__global__ void dec1_k(const float4* __restrict__ x, uint2* __restrict__ h, int n4) {
  int i = blockIdx.x * blockDim.x + threadIdx.x;
  const int stride = gridDim.x * blockDim.x;
  for (; i < n4; i += stride) {
    float4 v = x[i];
    uint2 hw;
    hw.x = (unsigned)f16_bits(v.x) | ((unsigned)f16_bits(v.y) << 16);
    hw.y = (unsigned)f16_bits(v.z) | ((unsigned)f16_bits(v.w) << 16);
    h[i] = hw;
  }
}

// ---------- decompose fp32 -> f16 hi/lo planes (for x2) ----------
__global__ void dec2_k(const float4* __restrict__ x, uint2* __restrict__ h,
                       uint2* __restrict__ l, int n4) {
  int i = blockIdx.x * blockDim.x + threadIdx.x;
  const int stride = gridDim.x * blockDim.x;
  for (; i < n4; i += stride) {
    float4 v = x[i];
    ushort h0, l0, h1, l1, h2, l2, h3, l3;
    split_f16(v.x, h0, l0); split_f16(v.y, h1, l1);
    split_f16(v.z, h2, l2); split_f16(v.w, h3, l3);
    uint2 hw, lw;
    hw.x = (unsigned)h0 | ((unsigned)h1 << 16); hw.y = (unsigned)h2 | ((unsigned)h3 << 16);
    lw.x = (unsigned)l0 | ((unsigned)l1 << 16); lw.y = (unsigned)l2 | ((unsigned)l3 << 16);
    h[i] = hw;
    l[i] = lw;
  }
}

// ---------- transpose + decompose U (scaled by 2048 to keep U_lo in f16 normal range) ----------
__global__ void transdec_k(const float* __restrict__ U,
                           ushort* __restrict__ UTh, ushort* __restrict__ UTl) {
  __shared__ float t[32][33];
  const int tx = threadIdx.x, ty = threadIdx.y;
  const int e0 = blockIdx.x * 32, d0 = blockIdx.y * 32;
#pragma unroll
  for (int r = 0; r < 4; ++r)
    t[ty + r * 8][tx] = U[(size_t)(d0 + ty + r * 8) * D_ + e0 + tx];
  __syncthreads();
#pragma unroll
  for (int r = 0; r < 4; ++r) {
    int e = ty + r * 8;
    ushort h, l;
    split_f16(t[tx][e] * 2048.0f, h, l);
    UTh[(size_t)(e0 + e) * D_ + d0 + tx] = h;
    UTl[(size_t)(e0 + e) * D_ + d0 + tx] = l;
  }
}

// ===== 256x256 tile GEMM core: BK=32, 8 waves (2x4), f16x2, 32x32x16 MFMA =====
// Triple-buffered LDS (3 x 24576 ushorts = 144KB): per buffer Ah | Bh | Bl planes.
// Rows of 32 ushorts = 4 x 16B slots; swizzle slot' = slot ^ ((row>>1)&3),
// applied on the GLOBAL source at stage time and on the ds_read address.
//
// ONE barrier + ONE counted vmcnt per K-tile; stage t+2 during tile t
// (2-tile lookahead; vmcnt(6) leaves planes(t+1) in flight, never drains).
// Per tile per wave: 16 ds_read_b128, 32 MFMA (2 passes x 2 ksteps x 4m x 2n).
struct CoreCtx {
  int w, lane, lane31, hi, swz, wm, wn;
  size_t soA;   // per-lane staging offset (ushorts) into a plane panel
};

__device__ __forceinline__ CoreCtx make_ctx() {
  CoreCtx c;
  const int tid = threadIdx.x;
  c.w = tid >> 6;
  c.lane = tid & 63;
  c.lane31 = c.lane & 31;
  c.hi = c.lane >> 5;
  c.swz = (c.lane31 >> 1) & 3;
  c.wm = c.w >> 2; c.wn = c.w & 3;   // wm: 128-row half, wn: 64-col quarter
  const int srow = c.lane >> 2;
  const int sslot = (c.lane & 3) ^ ((c.lane >> 3) & 3);
  c.soA = (size_t)(c.w * 32 + srow) * D_ + sslot * 8;
  return c;
}

// stage one 256x32 plane: wave w covers rows [w*32, w*32+32), 2 gl_lds ops
__device__ __forceinline__ void stage_plane(const ushort* src, ushort* dstbase,
                                            const CoreCtx& c, int k0) {
  const size_t a0 = c.soA + k0, a1 = a0 + (size_t)16 * D_;
  ushort* d0 = dstbase + c.w * 1024;
  gl_lds16(src + a0, d0);
  gl_lds16(src + a1, d0 + 512);
}

#define VMCNT(n) asm volatile("s_waitcnt vmcnt(" #n ")" ::: "memory")
#define BARRIER() do { asm volatile("" ::: "memory"); \
                       __builtin_amdgcn_s_barrier();  \
                       asm volatile("" ::: "memory"); } while (0)

__device__ __forceinline__ void core_loop(const CoreCtx& c,
    const ushort* Ah, const ushort* Bh, const ushort* Bl,
    ushort* lbuf, f32x16 acc[4][2])
{
  // prologue: stage tiles 0 and 1 (12 loads in flight)
  stage_plane(Ah, lbuf,                 c, 0);
  stage_plane(Bh, lbuf + 8192,          c, 0);
  stage_plane(Bl, lbuf + 16384,         c, 0);
  stage_plane(Ah, lbuf + 24576,         c, 32);
  stage_plane(Bh, lbuf + 24576 + 8192,  c, 32);
  stage_plane(Bl, lbuf + 24576 + 16384, c, 32);

  int bufsel = 0;
  for (int t = 0; t < 32; ++t) {
    const ushort* cb = lbuf + bufsel * 24576;
    int nb2 = bufsel + 2; if (nb2 >= 3) nb2 -= 3;
    ushort* nb = lbuf + nb2 * 24576;

    if (t < 31) { VMCNT(6); } else { VMCNT(0); }   // planes(t) landed; (t+1) may fly
    BARRIER();

    f16x8 a[4][2], bh4[2][2], bl4[2][2];
#pragma unroll
    for (int ks = 0; ks < 2; ++ks) {
      const int sl = ((((ks << 1) | c.hi) ^ c.swz) << 3);
#pragma unroll
      for (int mt = 0; mt < 4; ++mt) {
        const int r = c.wm * 128 + mt * 32 + c.lane31;
        a[mt][ks] = *(const f16x8*)&cb[r * 32 + sl];
      }
#pragma unroll
      for (int nt = 0; nt < 2; ++nt) {
        const int r = c.wn * 64 + nt * 32 + c.lane31;
        bh4[nt][ks] = *(const f16x8*)&cb[8192 + r * 32 + sl];
        bl4[nt][ks] = *(const f16x8*)&cb[16384 + r * 32 + sl];
      }
    }
    if (t < 30) {
      const int kn = (t + 2) * 32;
      stage_plane(Ah, nb, c, kn);
      stage_plane(Bh, nb + 8192, c, kn);
      stage_plane(Bl, nb + 16384, c, kn);
    }
    __builtin_amdgcn_s_setprio(1);
#pragma unroll
    for (int ks = 0; ks < 2; ++ks)
#pragma unroll
      for (int mt = 0; mt < 4; ++mt)
#pragma unroll
        for (int nt = 0; nt < 2; ++nt)
          acc[mt][nt] = __builtin_amdgcn_mfma_f32_32x32x16_f16(a[mt][ks], bh4[nt][ks], acc[mt][nt], 0, 0, 0);
#pragma unroll
    for (int ks = 0; ks < 2; ++ks)
#pragma unroll
      for (int mt = 0; mt < 4; ++mt)
#pragma unroll
        for (int nt = 0; nt < 2; ++nt)
          acc[mt][nt] = __builtin_amdgcn_mfma_f32_32x32x16_f16(a[mt][ks], bl4[nt][ks], acc[mt][nt], 0, 0, 0);
    __builtin_amdgcn_s_setprio(0);

    bufsel += 1; if (bufsel >= 3) bufsel -= 3;
  }
}

// C/D layout (32x32): col = lane&31, row = (reg&3) + 8*(reg>>2) + 4*(lane>>5)
#define CROW(r, hi) (((r) & 3) + 8 * ((r) >> 2) + 4 * (hi))

// ---------- GEMM1: Y = (x1 @ (U*2048)) / 2048 -> f16 hi plane ----------
__global__ __launch_bounds__(512, 2) void gemm1_k(
    const ushort* __restrict__ x1h,
    const ushort* __restrict__ UTh, const ushort* __restrict__ UTl,
    ushort* __restrict__ Yh)
{
  __shared__ __attribute__((aligned(16))) ushort lbuf[73728];
  const int z = blockIdx.z;
  const int orig = blockIdx.x;                 // 0..31
  const int xc = orig & 7, j = orig >> 3;      // j 0..3
  const int bx = (xc & 3) * 2 + (j & 1);       // 0..7
  const int by = (xc >> 2) * 2 + (j >> 1);     // 0..3

  const size_t zb = (size_t)z * (L_ * D_);
  const ushort* Ah = x1h + zb + (size_t)bx * 256 * D_;
  const ushort* Bh = UTh + (size_t)by * 256 * D_;
  const ushort* Bl = UTl + (size_t)by * 256 * D_;

  CoreCtx c = make_ctx();
  f32x16 acc[4][2];
#pragma unroll
  for (int mt = 0; mt < 4; ++mt)
#pragma unroll
    for (int nt = 0; nt < 2; ++nt)
#pragma unroll
      for (int r = 0; r < 16; ++r) acc[mt][nt][r] = 0.f;

  core_loop(c, Ah, Bh, Bl, lbuf, acc);

  __syncthreads();   // lbuf reused below

  // epilogue: unscale by 2^-11, convert to f16, LDS-coalesce, write Yh.
  // Per-wave region: 128 rows x 64 ushorts = 8192 ushorts.
  ushort* ep = lbuf + c.w * 8192;
  const int grow = bx * 256 + c.wm * 128;
  const int gcol = by * 256 + c.wn * 64;
#pragma unroll
  for (int mt = 0; mt < 4; ++mt)
#pragma unroll
    for (int nt = 0; nt < 2; ++nt)
#pragma unroll
      for (int r = 0; r < 16; ++r) {
        float v = acc[mt][nt][r] * 4.8828125e-4f;   // 1/2048
        const int row = mt * 32 + CROW(r, c.hi);
        ep[row * 64 + nt * 32 + c.lane31] = f16_bits(v);
      }
  // 128 rows x 64 ushorts, 8 chunks of 8 ushorts per row
#pragma unroll
  for (int q = 0; q < 16; ++q) {
    const int chunk = q * 64 + c.lane;
    const int row = chunk >> 3, c8 = (chunk & 7) * 8;
    f16x8 v = *(const f16x8*)&ep[row * 64 + c8];
    *(f16x8*)&Yh[zb + (size_t)(grow + row) * D_ + gcol + c8] = v;
  }
}

// ---------- GEMM2: M = Y @ x2^T, fused row/col max ----------
__global__ __launch_bounds__(512, 2) void gemm2_k(
    const ushort* __restrict__ Yh,
    const ushort* __restrict__ x2h, const ushort* __restrict__ x2l,
    unsigned* __restrict__ rmxg, unsigned* __restrict__ cmxg)
{
  __shared__ __attribute__((aligned(16))) ushort lbuf[73728];
  const int z = blockIdx.z;
  const int orig = blockIdx.x;                 // 0..63
  const int xc = orig & 7, j = orig >> 3;      // j 0..7
  const int bx = (xc & 3) * 2 + (j & 1);       // 0..7
  const int by = (xc >> 2) * 4 + (j >> 1);     // 0..7

  const size_t zb = (size_t)z * (L_ * D_);
  const ushort* Ah = Yh + zb + (size_t)bx * 256 * D_;
  const ushort* Bh = x2h + zb + (size_t)by * 256 * D_;
  const ushort* Bl = x2l + zb + (size_t)by * 256 * D_;

  CoreCtx c = make_ctx();
  f32x16 acc[4][2];
#pragma unroll
  for (int mt = 0; mt < 4; ++mt)
#pragma unroll
    for (int nt = 0; nt < 2; ++nt)
#pragma unroll
      for (int r = 0; r < 16; ++r) acc[mt][nt][r] = 0.f;

  core_loop(c, Ah, Bh, Bl, lbuf, acc);

  // epilogue: tile row/col max -> LDS atomics -> global atomics
  __syncthreads();
  unsigned* red = (unsigned*)lbuf;   // [0..255]=row max, [256..511]=col max
  const int tid = threadIdx.x;
  red[tid] = 0u;
  __syncthreads();

  // row max: for each reg, reduce across cols (lanes within 32-group)
#pragma unroll
  for (int mt = 0; mt < 4; ++mt) {
#pragma unroll
    for (int r = 0; r < 16; ++r) {
      float v = fmaxf(acc[mt][0][r], acc[mt][1][r]);
#pragma unroll
      for (int s = 1; s < 32; s <<= 1) v = fmaxf(v, __shfl_xor(v, s));
      if (c.lane31 == 0) {
        const int row = c.wm * 128 + mt * 32 + CROW(r, c.hi);
        atomicMax(&red[row], enc_f(v));
      }
    }
  }
  // col max: per lane over its regs, then combine hi halves
#pragma unroll
  for (int nt = 0; nt < 2; ++nt) {
    float v = -3.4e38f;
#pragma unroll
    for (int mt = 0; mt < 4; ++mt)
#pragma unroll
      for (int r = 0; r < 16; ++r) v = fmaxf(v, acc[mt][nt][r]);
    v = fmaxf(v, __shfl_xor(v, 32));
    if (c.hi == 0) atomicMax(&red[256 + c.wn * 64 + nt * 32 + c.lane31], enc_f(v));
  }
  __syncthreads();
  if (tid < 256) atomicMax(&rmxg[(size_t)z * L_ + bx * 256 + tid], red[tid]);
  else           atomicMax(&cmxg[(size_t)z * L_ + by * 256 + (tid - 256)], red[tid]);
}

// ---------- softmax over 2048 encoded maxima per batch ----------
__global__ void softmax_k(const unsigned* __restrict__ enc, float* __restrict__ w) {
  __shared__ float red[256];
  const int b = blockIdx.x, tid = threadIdx.x;
  const unsigned* e = enc + (size_t)b * L_;
  float* wb = w + (size_t)b * L_;
  float vals[8];
  float lmax = -3.4e38f;
#pragma unroll
  for (int q = 0; q < 8; ++q) {
    float f = dec_f(e[q * 256 + tid]);
    vals[q] = f;
    lmax = fmaxf(lmax, f);
  }
  red[tid] = lmax; __syncthreads();
  for (int s = 128; s > 0; s >>= 1) {
    if (tid < s) red[tid] = fmaxf(red[tid], red[tid + s]);
    __syncthreads();
  }
  const float mx = red[0];
  __syncthreads();
  float lsum = 0.f;
#pragma unroll
  for (int q = 0; q < 8; ++q) { vals[q] = expf(vals[q] - mx); lsum += vals[q]; }
  red[tid] = lsum; __syncthreads();
  for (int s = 128; s > 0; s >>= 1) {
    if (tid < s) red[tid] += red[tid + s];
    __syncthreads();
  }
  const float inv = 1.f / red[0];
#pragma unroll
  for (int q = 0; q < 8; ++q) wb[q * 256 + tid] = vals[q] * inv;
}

// ---------- weighted sum ----------
__global__ void wsum_k(const float* __restrict__ w, const float* __restrict__ x,
                       float* __restrict__ out) {
  __shared__ float ws[256];
  const int tid = threadIdx.x;
  const int b = blockIdx.y;
  const int i0 = blockIdx.x * 256;
  ws[tid] = w[(size_t)b * L_ + i0 + tid];
  __syncthreads();
  const int d0 = tid * 4;
  const float* xb = x + ((size_t)b * L_ + i0) * D_ + d0;
  float4 acc = {0.f, 0.f, 0.f, 0.f};
  for (int i = 0; i < 256; ++i) {
    float4 v = *(const float4*)(xb + (size_t)i * D_);
    float wi = ws[i];
    acc.x = fmaf(wi, v.x, acc.x);
    acc.y = fmaf(wi, v.y, acc.y);
    acc.z = fmaf(wi, v.z, acc.z);
    acc.w = fmaf(wi, v.w, acc.w);
  }
  float* o = out + (size_t)b * D_ + d0;
  atomicAdd(o + 0, acc.x);
  atomicAdd(o + 1, acc.y);
  atomicAdd(o + 2, acc.z);
  atomicAdd(o + 3, acc.w);
}

extern "C" void kernel_launch(void* const* d_in, const int* in_sizes, int n_in,
                              void* d_out, int out_size, void* d_ws, size_t ws_size,
                              hipStream_t stream) {
  (void)in_sizes; (void)n_in; (void)out_size;
  const float* x1 = (const float*)d_in[0];
  const float* x2 = (const float*)d_in[1];
  const float* U  = (const float*)d_in[2];
  float* out = (float*)d_out;

  // workspace layout
  char* p = (char*)d_ws;
  ushort* UTh = (ushort*)p; p += (size_t)D_ * D_ * 2;
  ushort* UTl = (ushort*)p; p += (size_t)D_ * D_ * 2;
  unsigned* rowmax = (unsigned*)p; p += (size_t)B_ * L_ * 4;
  unsigned* colmax = (unsigned*)p; p += (size_t)B_ * L_ * 4;
  float* w1 = (float*)p; p += (size_t)B_ * L_ * 4;
  float* w2 = (float*)p; p += (size_t)B_ * L_ * 4;
  const size_t fixed = (size_t)(p - (char*)d_ws);
  const size_t perB = (size_t)4 * L_ * D_ * 2;    // 4 f16 planes per batch = 16MB
  int G = 1;
  if (ws_size > fixed) {
    size_t g = (ws_size - fixed) / perB;
    G = g < 1 ? 1 : (g > (size_t)B_ ? B_ : (int)g);
  }
  ushort* x1h = (ushort*)p;
  ushort* x2h = x1h + (size_t)G * L_ * D_;
  ushort* x2l = x2h + (size_t)G * L_ * D_;
  ushort* Yh  = x2l + (size_t)G * L_ * D_;

  hipMemsetAsync(d_out, 0, (size_t)2 * B_ * D_ * 4, stream);
  hipMemsetAsync(rowmax, 0, (size_t)2 * B_ * L_ * 4, stream); // rowmax+colmax contiguous

  transdec_k<<<dim3(32, 32), dim3(32, 8), 0, stream>>>(U, UTh, UTl);

  for (int g0 = 0; g0 < B_; g0 += G) {
    const int Gc = (B_ - g0) < G ? (B_ - g0) : G;
    const int n4 = Gc * (L_ * D_ / 4);
    dec1_k<<<dim3(1024), 256, 0, stream>>>(
        (const float4*)(x1 + (size_t)g0 * L_ * D_), (uint2*)x1h, n4);
    dec2_k<<<dim3(1024), 256, 0, stream>>>(
        (const float4*)(x2 + (size_t)g0 * L_ * D_), (uint2*)x2h, (uint2*)x2l, n4);
    gemm1_k<<<dim3(32, 1, Gc), 512, 0, stream>>>(x1h, UTh, UTl, Yh);
    gemm2_k<<<dim3(64, 1, Gc), 512, 0, stream>>>(Yh, x2h, x2l,
        rowmax + (size_t)g0 * L_, colmax + (size_t)g0 * L_);
  }

  softmax_k<<<dim3(B_), 256, 0, stream>>>(rowmax, w1);
  softmax_k<<<dim3(B_), 256, 0, stream>>>(colmax, w2);
  wsum_k<<<dim3(8, B_), 256, 0, stream>>>(w1, x1, out);
  wsum_k<<<dim3(8, B_), 256, 0, stream>>>(w2, x2, out + (size_t)B_ * D_);
}

// Round 10
// 745.452 us; speedup vs baseline: 1.5895x; 1.5895x over previous
//
#include <hip/hip_runtime.h>
#include <hip/hip_bf16.h>
#include <stdint.h>

#define B_  32
#define L_  2048   // L1 == L2
#define D_  1024   // D1 == D2

typedef __attribute__((ext_vector_type(8))) _Float16 f16x8;
typedef __attribute__((ext_vector_type(4))) float f32x4;

// ---------- helpers ----------
__device__ __forceinline__ unsigned enc_f(float x) {
  unsigned u = __float_as_uint(x);
  return (u & 0x80000000u) ? ~u : (u | 0x80000000u);
}
__device__ __forceinline__ float dec_f(unsigned e) {
  unsigned u = (e & 0x80000000u) ? (e ^ 0x80000000u) : ~e;
  return __uint_as_float(u);
}
__device__ __forceinline__ ushort f16_bits(float x) {
  _Float16 h = (_Float16)x;               // RNE convert
  return __builtin_bit_cast(ushort, h);
}
__device__ __forceinline__ void split_f16(float x, ushort& h, ushort& l) {
  _Float16 hf = (_Float16)x;
  float r = x - (float)hf;
  h = __builtin_bit_cast(ushort, hf);
  l = __builtin_bit_cast(ushort, (_Float16)r);
}

// async global->LDS, 16B per lane; LDS dest wave-uniform, lane*16 placement.
__device__ __forceinline__ void gl_lds16(const ushort* g, ushort* l) {
  using gas_t = const __attribute__((address_space(1))) uint32_t*;
  using las_t = __attribute__((address_space(3))) uint32_t*;
  __builtin_amdgcn_global_load_lds((gas_t)(uintptr_t)g,
                                   (las_t)(unsigned)(uintptr_t)l, 16, 0, 0);
}

// ---------- decompose fp32 -> f16 hi plane only ----------
__global__ void dec1_k(const float4* __restrict__ x, uint2* __restrict__ h, int n4) {
  int i = blockIdx.x * blockDim.x + threadIdx.x;
  const int stride = gridDim.x * blockDim.x;
  for (; i < n4; i += stride) {
    float4 v = x[i];
    uint2 hw;
    hw.x = (unsigned)f16_bits(v.x) | ((unsigned)f16_bits(v.y) << 16);
    hw.y = (unsigned)f16_bits(v.z) | ((unsigned)f16_bits(v.w) << 16);
    h[i] = hw;
  }
}

// ---------- transpose + decompose U (scaled by 2048 to keep U_lo in f16 normal range) ----------
__global__ void transdec_k(const float* __restrict__ U,
                           ushort* __restrict__ UTh, ushort* __restrict__ UTl) {
  __shared__ float t[32][33];
  const int tx = threadIdx.x, ty = threadIdx.y;
  const int e0 = blockIdx.x * 32, d0 = blockIdx.y * 32;
#pragma unroll
  for (int r = 0; r < 4; ++r)
    t[ty + r * 8][tx] = U[(size_t)(d0 + ty + r * 8) * D_ + e0 + tx];
  __syncthreads();
#pragma unroll
  for (int r = 0; r < 4; ++r) {
    int e = ty + r * 8;
    ushort h, l;
    split_f16(t[tx][e] * 2048.0f, h, l);
    UTh[(size_t)(e0 + e) * D_ + d0 + tx] = h;
    UTl[(size_t)(e0 + e) * D_ + d0 + tx] = l;
  }
}

// ============ 256x256 tile GEMM cores: BK=32, 8 waves (2x4), f16 ============
// Rows of 32 ushorts = 4 x 16B slots; swizzle slot' = slot ^ ((row>>1)&3),
// applied on the GLOBAL source at stage time and on the ds_read address.
struct CoreCtx {
  int w, lane, ln, kq, wm, wn, ko;
  size_t soA;   // per-lane staging offset (ushorts) into a plane panel
};

__device__ __forceinline__ CoreCtx make_ctx() {
  CoreCtx c;
  const int tid = threadIdx.x;
  c.w = tid >> 6; c.lane = tid & 63;
  c.ln = c.lane & 15; c.kq = c.lane >> 4;
  c.wm = c.w >> 2; c.wn = c.w & 3;
  c.ko = (c.kq ^ ((c.ln >> 1) & 3)) * 8;
  const int srow = c.lane >> 2;
  const int sslot = (c.lane & 3) ^ ((c.lane >> 3) & 3);
  c.soA = (size_t)(c.w * 32 + srow) * D_ + sslot * 8;
  return c;
}

// stage one 256x32 plane: wave w covers rows [w*32, w*32+32), 2 gl_lds ops
__device__ __forceinline__ void stage_plane(const ushort* src, ushort* dstbase,
                                            const CoreCtx& c, int k0) {
  const size_t a0 = c.soA + k0, a1 = a0 + (size_t)16 * D_;
  ushort* d0 = dstbase + c.w * 1024;
  gl_lds16(src + a0, d0);
  gl_lds16(src + a1, d0 + 512);
}

#define VMCNT(n) asm volatile("s_waitcnt vmcnt(" #n ")" ::: "memory")
#define BARRIER() do { asm volatile("" ::: "memory"); \
                       __builtin_amdgcn_s_barrier();  \
                       asm volatile("" ::: "memory"); } while (0)

// --- gemm1 core: 3 planes (Ah | Bh | Bl), 2-phase counted-vmcnt (r8-proven) ---
__device__ __forceinline__ void core_loop3(const CoreCtx& c,
    const ushort* Ah, const ushort* Bh, const ushort* Bl,
    ushort* lbuf, f32x4 acc[8][4])
{
  stage_plane(Ah, lbuf,         c, 0);
  stage_plane(Bh, lbuf + 8192,  c, 0);
  stage_plane(Bl, lbuf + 16384, c, 0);

  for (int t = 0; t < 32; ++t) {
    const ushort* cb = lbuf + (t & 1) * 24576;
    ushort* nb = lbuf + ((t + 1) & 1) * 24576;
    const int kn = (t + 1) * 32;
    const bool pf = (t < 31);
    f16x8 a[8], bh4[4], bl4[4];

    // ---- phase 1: hh ----
    VMCNT(2);                       // Ah,Bh(t) landed; Bl(t) may fly
    BARRIER();
#pragma unroll
    for (int n = 0; n < 4; ++n) {
      const int r = c.wn * 64 + n * 16 + c.ln;
      bh4[n] = *(const f16x8*)&cb[8192 + r * 32 + c.ko];
    }
#pragma unroll
    for (int m = 0; m < 8; ++m) {
      const int r = c.wm * 128 + m * 16 + c.ln;
      a[m] = *(const f16x8*)&cb[r * 32 + c.ko];
    }
    if (pf) { stage_plane(Ah, nb, c, kn); stage_plane(Bh, nb + 8192, c, kn); }
    __builtin_amdgcn_s_setprio(1);
#pragma unroll
    for (int m = 0; m < 8; ++m)
#pragma unroll
      for (int n = 0; n < 4; ++n)
        acc[m][n] = __builtin_amdgcn_mfma_f32_16x16x32_f16(a[m], bh4[n], acc[m][n], 0, 0, 0);
    __builtin_amdgcn_s_setprio(0);

    // ---- phase 2: A_hi x B_lo ----
    if (pf) { VMCNT(4); } else { VMCNT(0); }   // Bl(t) landed
    BARRIER();
#pragma unroll
    for (int n = 0; n < 4; ++n) {
      const int r = c.wn * 64 + n * 16 + c.ln;
      bl4[n] = *(const f16x8*)&cb[16384 + r * 32 + c.ko];
    }
    if (pf) stage_plane(Bl, nb + 16384, c, kn);
    __builtin_amdgcn_s_setprio(1);
#pragma unroll
    for (int m = 0; m < 8; ++m)
#pragma unroll
      for (int n = 0; n < 4; ++n)
        acc[m][n] = __builtin_amdgcn_mfma_f32_16x16x32_f16(a[m], bl4[n], acc[m][n], 0, 0, 0);
    __builtin_amdgcn_s_setprio(0);
  }
}

// ---------- GEMM1: Y = (x1 @ (U*2048)) / 2048 -> f16 hi plane ----------
__global__ __launch_bounds__(512, 2) void gemm1_k(
    const ushort* __restrict__ x1h,
    const ushort* __restrict__ UTh, const ushort* __restrict__ UTl,
    ushort* __restrict__ Yh)
{
  __shared__ __attribute__((aligned(16))) ushort lbuf[65536];
  const int z = blockIdx.z;
  const int orig = blockIdx.x;                 // 0..31
  const int xc = orig & 7, j = orig >> 3;      // j 0..3
  const int bx = (xc & 3) * 2 + (j & 1);       // 0..7
  const int by = (xc >> 2) * 2 + (j >> 1);     // 0..3

  const size_t zb = (size_t)z * (L_ * D_);
  const ushort* Ah = x1h + zb + (size_t)bx * 256 * D_;
  const ushort* Bh = UTh + (size_t)by * 256 * D_;
  const ushort* Bl = UTl + (size_t)by * 256 * D_;

  CoreCtx c = make_ctx();
  f32x4 acc[8][4];
#pragma unroll
  for (int m = 0; m < 8; ++m)
#pragma unroll
    for (int n = 0; n < 4; ++n) acc[m][n] = (f32x4){0.f, 0.f, 0.f, 0.f};

  core_loop3(c, Ah, Bh, Bl, lbuf, acc);

  __syncthreads();   // lbuf reused below

  // epilogue: unscale by 2^-11, convert to f16, LDS-coalesce, write Yh.
  // Per-wave region: 128 rows x 64 ushorts = 8192 ushorts.
  ushort* ep = lbuf + c.w * 8192;
  const int grow = bx * 256 + c.wm * 128;
  const int gcol = by * 256 + c.wn * 64;
#pragma unroll
  for (int m = 0; m < 8; ++m)
#pragma unroll
    for (int n = 0; n < 4; ++n)
#pragma unroll
      for (int r2 = 0; r2 < 4; ++r2) {
        float v = acc[m][n][r2] * 4.8828125e-4f;   // 1/2048
        ep[(m * 16 + c.kq * 4 + r2) * 64 + n * 16 + c.ln] = f16_bits(v);
      }
#pragma unroll
  for (int q = 0; q < 16; ++q) {
    const int chunk = q * 64 + c.lane;
    const int row = chunk >> 3, c8 = (chunk & 7) * 8;
    f16x8 v = *(const f16x8*)&ep[row * 64 + c8];
    *(f16x8*)&Yh[zb + (size_t)(grow + row) * D_ + gcol + c8] = v;
  }
}

// ---------- GEMM2: M = Yh @ x2h^T (single f16 pass), fused row/col max ----------
__global__ __launch_bounds__(512, 2) void gemm2_k(
    const ushort* __restrict__ Yh,
    const ushort* __restrict__ x2h,
    unsigned* __restrict__ rmxg, unsigned* __restrict__ cmxg)
{
  __shared__ __attribute__((aligned(16))) ushort lbuf[32768];  // 64KB: 2 x (Ah|Bh)
  const int z = blockIdx.z;
  const int orig = blockIdx.x;                 // 0..63
  const int xc = orig & 7, j = orig >> 3;      // j 0..7
  const int bx = (xc & 3) * 2 + (j & 1);       // 0..7
  const int by = (xc >> 2) * 4 + (j >> 1);     // 0..7

  const size_t zb = (size_t)z * (L_ * D_);
  const ushort* Ah = Yh + zb + (size_t)bx * 256 * D_;
  const ushort* Bh = x2h + zb + (size_t)by * 256 * D_;

  CoreCtx c = make_ctx();
  f32x4 acc[8][4];
#pragma unroll
  for (int m = 0; m < 8; ++m)
#pragma unroll
    for (int n = 0; n < 4; ++n) acc[m][n] = (f32x4){0.f, 0.f, 0.f, 0.f};

  // prologue: stage tile 0
  stage_plane(Ah, lbuf,        c, 0);
  stage_plane(Bh, lbuf + 8192, c, 0);

  for (int t = 0; t < 32; ++t) {
    const ushort* cb = lbuf + (t & 1) * 16384;
    ushort* nb = lbuf + ((t + 1) & 1) * 16384;
    // issue next-tile stage BEFORE the wait (T4: counted, never drain mid-loop).
    // nb's previous readers finished at tile t-1's exit barrier.
    if (t < 31) {
      const int kn = (t + 1) * 32;
      stage_plane(Ah, nb, c, kn);
      stage_plane(Bh, nb + 8192, c, kn);
      VMCNT(4);                    // tile t's 4 loads landed; t+1's stay in flight
    } else {
      VMCNT(0);
    }
    BARRIER();
    f16x8 a[8], bh4[4];
#pragma unroll
    for (int n = 0; n < 4; ++n) {
      const int r = c.wn * 64 + n * 16 + c.ln;
      bh4[n] = *(const f16x8*)&cb[8192 + r * 32 + c.ko];
    }
#pragma unroll
    for (int m = 0; m < 8; ++m) {
      const int r = c.wm * 128 + m * 16 + c.ln;
      a[m] = *(const f16x8*)&cb[r * 32 + c.ko];
    }
    __builtin_amdgcn_s_setprio(1);
#pragma unroll
    for (int m = 0; m < 8; ++m)
#pragma unroll
      for (int n = 0; n < 4; ++n)
        acc[m][n] = __builtin_amdgcn_mfma_f32_16x16x32_f16(a[m], bh4[n], acc[m][n], 0, 0, 0);
    __builtin_amdgcn_s_setprio(0);
    BARRIER();   // exit: all reads of cb consumed before next tile stages into it
  }

  // epilogue: tile row/col max -> LDS atomics -> global atomics
  __syncthreads();
  unsigned* red = (unsigned*)lbuf;   // [0..255]=row max, [256..511]=col max
  const int tid = threadIdx.x;
  red[tid] = 0u;
  __syncthreads();

#pragma unroll
  for (int m = 0; m < 8; ++m) {
#pragma unroll
    for (int r2 = 0; r2 < 4; ++r2) {
      float v = fmaxf(fmaxf(acc[m][0][r2], acc[m][1][r2]),
                      fmaxf(acc[m][2][r2], acc[m][3][r2]));
#pragma unroll
      for (int s = 1; s < 16; s <<= 1) v = fmaxf(v, __shfl_xor(v, s));
      if (c.ln == 0) atomicMax(&red[c.wm * 128 + m * 16 + c.kq * 4 + r2], enc_f(v));
    }
  }
#pragma unroll
  for (int n = 0; n < 4; ++n) {
    float v = -3.4e38f;
#pragma unroll
    for (int m = 0; m < 8; ++m)
#pragma unroll
      for (int r2 = 0; r2 < 4; ++r2) v = fmaxf(v, acc[m][n][r2]);
    v = fmaxf(v, __shfl_xor(v, 16));
    v = fmaxf(v, __shfl_xor(v, 32));
    if (c.kq == 0) atomicMax(&red[256 + c.wn * 64 + n * 16 + c.ln], enc_f(v));
  }
  __syncthreads();
  if (tid < 256) atomicMax(&rmxg[(size_t)z * L_ + bx * 256 + tid], red[tid]);
  else           atomicMax(&cmxg[(size_t)z * L_ + by * 256 + (tid - 256)], red[tid]);
}

// ---------- softmax over 2048 encoded maxima per batch ----------
__global__ void softmax_k(const unsigned* __restrict__ enc, float* __restrict__ w) {
  __shared__ float red[256];
  const int b = blockIdx.x, tid = threadIdx.x;
  const unsigned* e = enc + (size_t)b * L_;
  float* wb = w + (size_t)b * L_;
  float vals[8];
  float lmax = -3.4e38f;
#pragma unroll
  for (int q = 0; q < 8; ++q) {
    float f = dec_f(e[q * 256 + tid]);
    vals[q] = f;
    lmax = fmaxf(lmax, f);
  }
  red[tid] = lmax; __syncthreads();
  for (int s = 128; s > 0; s >>= 1) {
    if (tid < s) red[tid] = fmaxf(red[tid], red[tid + s]);
    __syncthreads();
  }
  const float mx = red[0];
  __syncthreads();
  float lsum = 0.f;
#pragma unroll
  for (int q = 0; q < 8; ++q) { vals[q] = expf(vals[q] - mx); lsum += vals[q]; }
  red[tid] = lsum; __syncthreads();
  for (int s = 128; s > 0; s >>= 1) {
    if (tid < s) red[tid] += red[tid + s];
    __syncthreads();
  }
  const float inv = 1.f / red[0];
#pragma unroll
  for (int q = 0; q < 8; ++q) wb[q * 256 + tid] = vals[q] * inv;
}

// ---------- weighted sum (f16 input planes) ----------
__global__ void wsum_k(const float* __restrict__ w, const ushort* __restrict__ xh,
                       float* __restrict__ out) {
  __shared__ float ws[256];
  const int tid = threadIdx.x;
  const int b = blockIdx.y;
  const int i0 = blockIdx.x * 256;
  ws[tid] = w[(size_t)b * L_ + i0 + tid];
  __syncthreads();
  const int d0 = tid * 4;
  const ushort* xb = xh + ((size_t)b * L_ + i0) * D_ + d0;
  float4 acc = {0.f, 0.f, 0.f, 0.f};
  for (int i = 0; i < 256; ++i) {
    ushort4 v = *(const ushort4*)(xb + (size_t)i * D_);
    float wi = ws[i];
    acc.x = fmaf(wi, (float)__builtin_bit_cast(_Float16, v.x), acc.x);
    acc.y = fmaf(wi, (float)__builtin_bit_cast(_Float16, v.y), acc.y);
    acc.z = fmaf(wi, (float)__builtin_bit_cast(_Float16, v.z), acc.z);
    acc.w = fmaf(wi, (float)__builtin_bit_cast(_Float16, v.w), acc.w);
  }
  float* o = out + (size_t)b * D_ + d0;
  atomicAdd(o + 0, acc.x);
  atomicAdd(o + 1, acc.y);
  atomicAdd(o + 2, acc.z);
  atomicAdd(o + 3, acc.w);
}

extern "C" void kernel_launch(void* const* d_in, const int* in_sizes, int n_in,
                              void* d_out, int out_size, void* d_ws, size_t ws_size,
                              hipStream_t stream) {
  (void)in_sizes; (void)n_in; (void)out_size;
  const float* x1 = (const float*)d_in[0];
  const float* x2 = (const float*)d_in[1];
  const float* U  = (const float*)d_in[2];
  float* out = (float*)d_out;

  // workspace layout
  char* p = (char*)d_ws;
  ushort* UTh = (ushort*)p; p += (size_t)D_ * D_ * 2;
  ushort* UTl = (ushort*)p; p += (size_t)D_ * D_ * 2;
  unsigned* rowmax = (unsigned*)p; p += (size_t)B_ * L_ * 4;
  unsigned* colmax = (unsigned*)p; p += (size_t)B_ * L_ * 4;
  float* w1 = (float*)p; p += (size_t)B_ * L_ * 4;
  float* w2 = (float*)p; p += (size_t)B_ * L_ * 4;
  const size_t fixed = (size_t)(p - (char*)d_ws);
  const size_t perB = (size_t)3 * L_ * D_ * 2;    // 3 f16 planes per batch = 12MB
  int G = 1;
  if (ws_size > fixed) {
    size_t g = (ws_size - fixed) / perB;
    G = g < 1 ? 1 : (g > (size_t)B_ ? B_ : (int)g);
  }
  ushort* x1h = (ushort*)p;
  ushort* x2h = x1h + (size_t)G * L_ * D_;
  ushort* Yh  = x2h + (size_t)G * L_ * D_;

  hipMemsetAsync(d_out, 0, (size_t)2 * B_ * D_ * 4, stream);
  hipMemsetAsync(rowmax, 0, (size_t)2 * B_ * L_ * 4, stream); // rowmax+colmax contiguous

  transdec_k<<<dim3(32, 32), dim3(32, 8), 0, stream>>>(U, UTh, UTl);

  for (int g0 = 0; g0 < B_; g0 += G) {
    const int Gc = (B_ - g0) < G ? (B_ - g0) : G;
    const int n4 = Gc * (L_ * D_ / 4);
    dec1_k<<<dim3(1024), 256, 0, stream>>>(
        (const float4*)(x1 + (size_t)g0 * L_ * D_), (uint2*)x1h, n4);
    dec1_k<<<dim3(1024), 256, 0, stream>>>(
        (const float4*)(x2 + (size_t)g0 * L_ * D_), (uint2*)x2h, n4);
    gemm1_k<<<dim3(32, 1, Gc), 512, 0, stream>>>(x1h, UTh, UTl, Yh);
    gemm2_k<<<dim3(64, 1, Gc), 512, 0, stream>>>(Yh, x2h,
        rowmax + (size_t)g0 * L_, colmax + (size_t)g0 * L_);
    // per-group softmax + weighted sums (f16 planes are group-local)
    softmax_k<<<dim3(Gc), 256, 0, stream>>>(rowmax + (size_t)g0 * L_,
                                            w1 + (size_t)g0 * L_);
    softmax_k<<<dim3(Gc), 256, 0, stream>>>(colmax + (size_t)g0 * L_,
                                            w2 + (size_t)g0 * L_);
    wsum_k<<<dim3(8, Gc), 256, 0, stream>>>(w1 + (size_t)g0 * L_, x1h,
                                            out + (size_t)g0 * D_);
    wsum_k<<<dim3(8, Gc), 256, 0, stream>>>(w2 + (size_t)g0 * L_, x2h,
                                            out + (size_t)(B_ + g0) * D_);
  }
}

// Round 11
// 737.785 us; speedup vs baseline: 1.6061x; 1.0104x over previous
//
#include <hip/hip_runtime.h>
#include <hip/hip_bf16.h>
#include <stdint.h>

#define B_  32
#define L_  2048   // L1 == L2
#define D_  1024   // D1 == D2

typedef __attribute__((ext_vector_type(8))) _Float16 f16x8;
typedef __attribute__((ext_vector_type(4))) float f32x4;

// ---------- helpers ----------
__device__ __forceinline__ unsigned enc_f(float x) {
  unsigned u = __float_as_uint(x);
  return (u & 0x80000000u) ? ~u : (u | 0x80000000u);
}
__device__ __forceinline__ float dec_f(unsigned e) {
  unsigned u = (e & 0x80000000u) ? (e ^ 0x80000000u) : ~e;
  return __uint_as_float(u);
}
__device__ __forceinline__ ushort f16_bits(float x) {
  _Float16 h = (_Float16)x;               // RNE convert
  return __builtin_bit_cast(ushort, h);
}
__device__ __forceinline__ void split_f16(float x, ushort& h, ushort& l) {
  _Float16 hf = (_Float16)x;
  float r = x - (float)hf;
  h = __builtin_bit_cast(ushort, hf);
  l = __builtin_bit_cast(ushort, (_Float16)r);
}

// async global->LDS, 16B per lane; LDS dest wave-uniform, lane*16 placement.
__device__ __forceinline__ void gl_lds16(const ushort* g, ushort* l) {
  using gas_t = const __attribute__((address_space(1))) uint32_t*;
  using las_t = __attribute__((address_space(3))) uint32_t*;
  __builtin_amdgcn_global_load_lds((gas_t)(uintptr_t)g,
                                   (las_t)(unsigned)(uintptr_t)l, 16, 0, 0);
}

// ---------- decompose fp32 -> f16 hi plane only ----------
__global__ void dec1_k(const float4* __restrict__ x, uint2* __restrict__ h, int n4) {
  int i = blockIdx.x * blockDim.x + threadIdx.x;
  const int stride = gridDim.x * blockDim.x;
  for (; i < n4; i += stride) {
    float4 v = x[i];
    uint2 hw;
    hw.x = (unsigned)f16_bits(v.x) | ((unsigned)f16_bits(v.y) << 16);
    hw.y = (unsigned)f16_bits(v.z) | ((unsigned)f16_bits(v.w) << 16);
    h[i] = hw;
  }
}

// ---------- transpose + decompose U (scaled by 2048 to keep U_lo in f16 normal range) ----------
__global__ void transdec_k(const float* __restrict__ U,
                           ushort* __restrict__ UTh, ushort* __restrict__ UTl) {
  __shared__ float t[32][33];
  const int tx = threadIdx.x, ty = threadIdx.y;
  const int e0 = blockIdx.x * 32, d0 = blockIdx.y * 32;
#pragma unroll
  for (int r = 0; r < 4; ++r)
    t[ty + r * 8][tx] = U[(size_t)(d0 + ty + r * 8) * D_ + e0 + tx];
  __syncthreads();
#pragma unroll
  for (int r = 0; r < 4; ++r) {
    int e = ty + r * 8;
    ushort h, l;
    split_f16(t[tx][e] * 2048.0f, h, l);
    UTh[(size_t)(e0 + e) * D_ + d0 + tx] = h;
    UTl[(size_t)(e0 + e) * D_ + d0 + tx] = l;
  }
}

// ============ 256x256 tile GEMM cores: 8 waves (2x4), f16 ============
struct CoreCtx {
  int w, lane, ln, kq, wm, wn, ko;
  size_t soA;     // BK=32 staging offset (gemm1)
  size_t soA64;   // BK=64 staging offset (gemm2)
  int ko64_0, ko64_1;  // BK=64 ds_read k-offsets for kh=0,1
};

__device__ __forceinline__ CoreCtx make_ctx() {
  CoreCtx c;
  const int tid = threadIdx.x;
  c.w = tid >> 6; c.lane = tid & 63;
  c.ln = c.lane & 15; c.kq = c.lane >> 4;
  c.wm = c.w >> 2; c.wn = c.w & 3;
  // BK=32 (rows of 32 ushorts, 4 slots, swizzle slot^((row>>1)&3))
  c.ko = (c.kq ^ ((c.ln >> 1) & 3)) * 8;
  const int srow = c.lane >> 2;
  const int sslot = (c.lane & 3) ^ ((c.lane >> 3) & 3);
  c.soA = (size_t)(c.w * 32 + srow) * D_ + sslot * 8;
  // BK=64 (rows of 64 ushorts, 8 slots, swizzle slot^(row&7); row&7 == ln&7 on reads)
  const int p = c.ln & 7;
  c.ko64_0 = ((c.kq + 0) ^ p) * 8;
  c.ko64_1 = ((c.kq + 4) ^ p) * 8;
  const int srow8 = c.lane >> 3;
  const int sslot8 = (c.lane & 7) ^ srow8;
  c.soA64 = (size_t)(c.w * 32 + srow8) * D_ + sslot8 * 8;
  return c;
}

// stage one 256x32 plane (BK=32): wave w covers rows [w*32, w*32+32), 2 gl_lds
__device__ __forceinline__ void stage_plane(const ushort* src, ushort* dstbase,
                                            const CoreCtx& c, int k0) {
  const size_t a0 = c.soA + k0, a1 = a0 + (size_t)16 * D_;
  ushort* d0 = dstbase + c.w * 1024;
  gl_lds16(src + a0, d0);
  gl_lds16(src + a1, d0 + 512);
}

// stage one 256x64 plane (BK=64): wave w covers rows [w*32, w*32+32), 4 gl_lds
__device__ __forceinline__ void stage_plane64(const ushort* src, ushort* dstbase,
                                              const CoreCtx& c, int k0) {
  const size_t a = c.soA64 + k0;
  ushort* d = dstbase + c.w * 2048;
  gl_lds16(src + a, d);
  gl_lds16(src + a + (size_t)8 * D_,  d + 512);
  gl_lds16(src + a + (size_t)16 * D_, d + 1024);
  gl_lds16(src + a + (size_t)24 * D_, d + 1536);
}

#define VMCNT(n) asm volatile("s_waitcnt vmcnt(" #n ")" ::: "memory")
#define BARRIER() do { asm volatile("" ::: "memory"); \
                       __builtin_amdgcn_s_barrier();  \
                       asm volatile("" ::: "memory"); } while (0)

// --- gemm1 core: 3 planes (Ah | Bh | Bl), BK=32, 2-phase counted-vmcnt (r8-proven) ---
__device__ __forceinline__ void core_loop3(const CoreCtx& c,
    const ushort* Ah, const ushort* Bh, const ushort* Bl,
    ushort* lbuf, f32x4 acc[8][4])
{
  stage_plane(Ah, lbuf,         c, 0);
  stage_plane(Bh, lbuf + 8192,  c, 0);
  stage_plane(Bl, lbuf + 16384, c, 0);

  for (int t = 0; t < 32; ++t) {
    const ushort* cb = lbuf + (t & 1) * 24576;
    ushort* nb = lbuf + ((t + 1) & 1) * 24576;
    const int kn = (t + 1) * 32;
    const bool pf = (t < 31);
    f16x8 a[8], bh4[4], bl4[4];

    // ---- phase 1: hh ----
    VMCNT(2);                       // Ah,Bh(t) landed; Bl(t) may fly
    BARRIER();
#pragma unroll
    for (int n = 0; n < 4; ++n) {
      const int r = c.wn * 64 + n * 16 + c.ln;
      bh4[n] = *(const f16x8*)&cb[8192 + r * 32 + c.ko];
    }
#pragma unroll
    for (int m = 0; m < 8; ++m) {
      const int r = c.wm * 128 + m * 16 + c.ln;
      a[m] = *(const f16x8*)&cb[r * 32 + c.ko];
    }
    if (pf) { stage_plane(Ah, nb, c, kn); stage_plane(Bh, nb + 8192, c, kn); }
    __builtin_amdgcn_s_setprio(1);
#pragma unroll
    for (int m = 0; m < 8; ++m)
#pragma unroll
      for (int n = 0; n < 4; ++n)
        acc[m][n] = __builtin_amdgcn_mfma_f32_16x16x32_f16(a[m], bh4[n], acc[m][n], 0, 0, 0);
    __builtin_amdgcn_s_setprio(0);

    // ---- phase 2: A_hi x B_lo ----
    if (pf) { VMCNT(4); } else { VMCNT(0); }   // Bl(t) landed
    BARRIER();
#pragma unroll
    for (int n = 0; n < 4; ++n) {
      const int r = c.wn * 64 + n * 16 + c.ln;
      bl4[n] = *(const f16x8*)&cb[16384 + r * 32 + c.ko];
    }
    if (pf) stage_plane(Bl, nb + 16384, c, kn);
    __builtin_amdgcn_s_setprio(1);
#pragma unroll
    for (int m = 0; m < 8; ++m)
#pragma unroll
      for (int n = 0; n < 4; ++n)
        acc[m][n] = __builtin_amdgcn_mfma_f32_16x16x32_f16(a[m], bl4[n], acc[m][n], 0, 0, 0);
    __builtin_amdgcn_s_setprio(0);
  }
}

// ---------- GEMM1: Y = (x1 @ (U*2048)) / 2048 -> f16 hi plane ----------
__global__ __launch_bounds__(512, 2) void gemm1_k(
    const ushort* __restrict__ x1h,
    const ushort* __restrict__ UTh, const ushort* __restrict__ UTl,
    ushort* __restrict__ Yh)
{
  __shared__ __attribute__((aligned(16))) ushort lbuf[65536];
  const int z = blockIdx.z;
  const int orig = blockIdx.x;                 // 0..31
  const int xc = orig & 7, j = orig >> 3;      // j 0..3
  const int bx = (xc & 3) * 2 + (j & 1);       // 0..7
  const int by = (xc >> 2) * 2 + (j >> 1);     // 0..3

  const size_t zb = (size_t)z * (L_ * D_);
  const ushort* Ah = x1h + zb + (size_t)bx * 256 * D_;
  const ushort* Bh = UTh + (size_t)by * 256 * D_;
  const ushort* Bl = UTl + (size_t)by * 256 * D_;

  CoreCtx c = make_ctx();
  f32x4 acc[8][4];
#pragma unroll
  for (int m = 0; m < 8; ++m)
#pragma unroll
    for (int n = 0; n < 4; ++n) acc[m][n] = (f32x4){0.f, 0.f, 0.f, 0.f};

  core_loop3(c, Ah, Bh, Bl, lbuf, acc);

  __syncthreads();   // lbuf reused below

  // epilogue: unscale by 2^-11, convert to f16, LDS-coalesce, write Yh.
  ushort* ep = lbuf + c.w * 8192;
  const int grow = bx * 256 + c.wm * 128;
  const int gcol = by * 256 + c.wn * 64;
#pragma unroll
  for (int m = 0; m < 8; ++m)
#pragma unroll
    for (int n = 0; n < 4; ++n)
#pragma unroll
      for (int r2 = 0; r2 < 4; ++r2) {
        float v = acc[m][n][r2] * 4.8828125e-4f;   // 1/2048
        ep[(m * 16 + c.kq * 4 + r2) * 64 + n * 16 + c.ln] = f16_bits(v);
      }
#pragma unroll
  for (int q = 0; q < 16; ++q) {
    const int chunk = q * 64 + c.lane;
    const int row = chunk >> 3, c8 = (chunk & 7) * 8;
    f16x8 v = *(const f16x8*)&ep[row * 64 + c8];
    *(f16x8*)&Yh[zb + (size_t)(grow + row) * D_ + gcol + c8] = v;
  }
}

// ---------- GEMM2: M = Yh @ x2h^T (single f16 pass, BK=64), fused row/col max ----------
__global__ __launch_bounds__(512, 2) void gemm2_k(
    const ushort* __restrict__ Yh,
    const ushort* __restrict__ x2h,
    unsigned* __restrict__ rmxg, unsigned* __restrict__ cmxg)
{
  __shared__ __attribute__((aligned(16))) ushort lbuf[65536];  // 128KB: 2 x (Ah|Bh) BK=64
  const int z = blockIdx.z;
  const int orig = blockIdx.x;                 // 0..63
  const int xc = orig & 7, j = orig >> 3;      // j 0..7
  const int bx = (xc & 3) * 2 + (j & 1);       // 0..7
  const int by = (xc >> 2) * 4 + (j >> 1);     // 0..7

  const size_t zb = (size_t)z * (L_ * D_);
  const ushort* Ah = Yh + zb + (size_t)bx * 256 * D_;
  const ushort* Bh = x2h + zb + (size_t)by * 256 * D_;

  CoreCtx c = make_ctx();
  f32x4 acc[8][4];
#pragma unroll
  for (int m = 0; m < 8; ++m)
#pragma unroll
    for (int n = 0; n < 4; ++n) acc[m][n] = (f32x4){0.f, 0.f, 0.f, 0.f};

  // prologue: stage tile 0 (8 loads in flight)
  stage_plane64(Ah, lbuf,         c, 0);
  stage_plane64(Bh, lbuf + 16384, c, 0);

  for (int t = 0; t < 16; ++t) {
    const ushort* cb = lbuf + (t & 1) * 32768;
    ushort* nb = lbuf + ((t + 1) & 1) * 32768;
    // issue next-tile stage BEFORE the wait (counted vmcnt, never drains mid-loop)
    if (t < 15) {
      const int kn = (t + 1) * 64;
      stage_plane64(Ah, nb, c, kn);
      stage_plane64(Bh, nb + 16384, c, kn);
      VMCNT(8);                    // tile t's 8 loads landed; t+1's stay in flight
    } else {
      VMCNT(0);
    }
    BARRIER();
    f16x8 a0[8], b0[4], a1[8], b1[4];
#pragma unroll
    for (int n = 0; n < 4; ++n) {
      const int r = c.wn * 64 + n * 16 + c.ln;
      b0[n] = *(const f16x8*)&cb[16384 + r * 64 + c.ko64_0];
      b1[n] = *(const f16x8*)&cb[16384 + r * 64 + c.ko64_1];
    }
#pragma unroll
    for (int m = 0; m < 8; ++m) {
      const int r = c.wm * 128 + m * 16 + c.ln;
      a0[m] = *(const f16x8*)&cb[r * 64 + c.ko64_0];
      a1[m] = *(const f16x8*)&cb[r * 64 + c.ko64_1];
    }
    __builtin_amdgcn_s_setprio(1);
#pragma unroll
    for (int m = 0; m < 8; ++m)
#pragma unroll
      for (int n = 0; n < 4; ++n)
        acc[m][n] = __builtin_amdgcn_mfma_f32_16x16x32_f16(a0[m], b0[n], acc[m][n], 0, 0, 0);
#pragma unroll
    for (int m = 0; m < 8; ++m)
#pragma unroll
      for (int n = 0; n < 4; ++n)
        acc[m][n] = __builtin_amdgcn_mfma_f32_16x16x32_f16(a1[m], b1[n], acc[m][n], 0, 0, 0);
    __builtin_amdgcn_s_setprio(0);
    BARRIER();   // all reads of cb consumed before next tile stages into it
  }

  // epilogue: tile row/col max -> LDS atomics -> global atomics
  __syncthreads();
  unsigned* red = (unsigned*)lbuf;   // [0..255]=row max, [256..511]=col max
  const int tid = threadIdx.x;
  red[tid] = 0u;
  __syncthreads();

#pragma unroll
  for (int m = 0; m < 8; ++m) {
#pragma unroll
    for (int r2 = 0; r2 < 4; ++r2) {
      float v = fmaxf(fmaxf(acc[m][0][r2], acc[m][1][r2]),
                      fmaxf(acc[m][2][r2], acc[m][3][r2]));
#pragma unroll
      for (int s = 1; s < 16; s <<= 1) v = fmaxf(v, __shfl_xor(v, s));
      if (c.ln == 0) atomicMax(&red[c.wm * 128 + m * 16 + c.kq * 4 + r2], enc_f(v));
    }
  }
#pragma unroll
  for (int n = 0; n < 4; ++n) {
    float v = -3.4e38f;
#pragma unroll
    for (int m = 0; m < 8; ++m)
#pragma unroll
      for (int r2 = 0; r2 < 4; ++r2) v = fmaxf(v, acc[m][n][r2]);
    v = fmaxf(v, __shfl_xor(v, 16));
    v = fmaxf(v, __shfl_xor(v, 32));
    if (c.kq == 0) atomicMax(&red[256 + c.wn * 64 + n * 16 + c.ln], enc_f(v));
  }
  __syncthreads();
  if (tid < 256) atomicMax(&rmxg[(size_t)z * L_ + bx * 256 + tid], red[tid]);
  else           atomicMax(&cmxg[(size_t)z * L_ + by * 256 + (tid - 256)], red[tid]);
}

// ---------- softmax over 2048 encoded maxima per batch ----------
__global__ void softmax_k(const unsigned* __restrict__ enc, float* __restrict__ w) {
  __shared__ float red[256];
  const int b = blockIdx.x, tid = threadIdx.x;
  const unsigned* e = enc + (size_t)b * L_;
  float* wb = w + (size_t)b * L_;
  float vals[8];
  float lmax = -3.4e38f;
#pragma unroll
  for (int q = 0; q < 8; ++q) {
    float f = dec_f(e[q * 256 + tid]);
    vals[q] = f;
    lmax = fmaxf(lmax, f);
  }
  red[tid] = lmax; __syncthreads();
  for (int s = 128; s > 0; s >>= 1) {
    if (tid < s) red[tid] = fmaxf(red[tid], red[tid + s]);
    __syncthreads();
  }
  const float mx = red[0];
  __syncthreads();
  float lsum = 0.f;
#pragma unroll
  for (int q = 0; q < 8; ++q) { vals[q] = expf(vals[q] - mx); lsum += vals[q]; }
  red[tid] = lsum; __syncthreads();
  for (int s = 128; s > 0; s >>= 1) {
    if (tid < s) red[tid] += red[tid + s];
    __syncthreads();
  }
  const float inv = 1.f / red[0];
#pragma unroll
  for (int q = 0; q < 8; ++q) wb[q * 256 + tid] = vals[q] * inv;
}

// ---------- weighted sum (f16 input planes) ----------
__global__ void wsum_k(const float* __restrict__ w, const ushort* __restrict__ xh,
                       float* __restrict__ out) {
  __shared__ float ws[256];
  const int tid = threadIdx.x;
  const int b = blockIdx.y;
  const int i0 = blockIdx.x * 256;
  ws[tid] = w[(size_t)b * L_ + i0 + tid];
  __syncthreads();
  const int d0 = tid * 4;
  const ushort* xb = xh + ((size_t)b * L_ + i0) * D_ + d0;
  float4 acc = {0.f, 0.f, 0.f, 0.f};
  for (int i = 0; i < 256; ++i) {
    ushort4 v = *(const ushort4*)(xb + (size_t)i * D_);
    float wi = ws[i];
    acc.x = fmaf(wi, (float)__builtin_bit_cast(_Float16, v.x), acc.x);
    acc.y = fmaf(wi, (float)__builtin_bit_cast(_Float16, v.y), acc.y);
    acc.z = fmaf(wi, (float)__builtin_bit_cast(_Float16, v.z), acc.z);
    acc.w = fmaf(wi, (float)__builtin_bit_cast(_Float16, v.w), acc.w);
  }
  float* o = out + (size_t)b * D_ + d0;
  atomicAdd(o + 0, acc.x);
  atomicAdd(o + 1, acc.y);
  atomicAdd(o + 2, acc.z);
  atomicAdd(o + 3, acc.w);
}

extern "C" void kernel_launch(void* const* d_in, const int* in_sizes, int n_in,
                              void* d_out, int out_size, void* d_ws, size_t ws_size,
                              hipStream_t stream) {
  (void)in_sizes; (void)n_in; (void)out_size;
  const float* x1 = (const float*)d_in[0];
  const float* x2 = (const float*)d_in[1];
  const float* U  = (const float*)d_in[2];
  float* out = (float*)d_out;

  // workspace layout
  char* p = (char*)d_ws;
  ushort* UTh = (ushort*)p; p += (size_t)D_ * D_ * 2;
  ushort* UTl = (ushort*)p; p += (size_t)D_ * D_ * 2;
  unsigned* rowmax = (unsigned*)p; p += (size_t)B_ * L_ * 4;
  unsigned* colmax = (unsigned*)p; p += (size_t)B_ * L_ * 4;
  float* w1 = (float*)p; p += (size_t)B_ * L_ * 4;
  float* w2 = (float*)p; p += (size_t)B_ * L_ * 4;
  const size_t fixed = (size_t)(p - (char*)d_ws);
  const size_t perB = (size_t)3 * L_ * D_ * 2;    // 3 f16 planes per batch = 12MB
  int G = 1;
  if (ws_size > fixed) {
    size_t g = (ws_size - fixed) / perB;
    G = g < 1 ? 1 : (g > (size_t)B_ ? B_ : (int)g);
  }
  ushort* x1h = (ushort*)p;
  ushort* x2h = x1h + (size_t)G * L_ * D_;
  ushort* Yh  = x2h + (size_t)G * L_ * D_;

  hipMemsetAsync(d_out, 0, (size_t)2 * B_ * D_ * 4, stream);
  hipMemsetAsync(rowmax, 0, (size_t)2 * B_ * L_ * 4, stream); // rowmax+colmax contiguous

  transdec_k<<<dim3(32, 32), dim3(32, 8), 0, stream>>>(U, UTh, UTl);

  for (int g0 = 0; g0 < B_; g0 += G) {
    const int Gc = (B_ - g0) < G ? (B_ - g0) : G;
    const int n4 = Gc * (L_ * D_ / 4);
    dec1_k<<<dim3(1024), 256, 0, stream>>>(
        (const float4*)(x1 + (size_t)g0 * L_ * D_), (uint2*)x1h, n4);
    dec1_k<<<dim3(1024), 256, 0, stream>>>(
        (const float4*)(x2 + (size_t)g0 * L_ * D_), (uint2*)x2h, n4);
    gemm1_k<<<dim3(32, 1, Gc), 512, 0, stream>>>(x1h, UTh, UTl, Yh);
    gemm2_k<<<dim3(64, 1, Gc), 512, 0, stream>>>(Yh, x2h,
        rowmax + (size_t)g0 * L_, colmax + (size_t)g0 * L_);
    // per-group softmax + weighted sums (f16 planes are group-local)
    softmax_k<<<dim3(Gc), 256, 0, stream>>>(rowmax + (size_t)g0 * L_,
                                            w1 + (size_t)g0 * L_);
    softmax_k<<<dim3(Gc), 256, 0, stream>>>(colmax + (size_t)g0 * L_,
                                            w2 + (size_t)g0 * L_);
    wsum_k<<<dim3(8, Gc), 256, 0, stream>>>(w1 + (size_t)g0 * L_, x1h,
                                            out + (size_t)g0 * D_);
    wsum_k<<<dim3(8, Gc), 256, 0, stream>>>(w2 + (size_t)g0 * L_, x2h,
                                            out + (size_t)(B_ + g0) * D_);
  }
}

// Round 12
// 724.669 us; speedup vs baseline: 1.6351x; 1.0181x over previous
//
#include <hip/hip_runtime.h>
#include <hip/hip_bf16.h>
#include <stdint.h>

#define B_  32
#define L_  2048   // L1 == L2
#define D_  1024   // D1 == D2

typedef __attribute__((ext_vector_type(8))) _Float16 f16x8;
typedef __attribute__((ext_vector_type(4))) float f32x4;

// ---------- helpers ----------
__device__ __forceinline__ unsigned enc_f(float x) {
  unsigned u = __float_as_uint(x);
  return (u & 0x80000000u) ? ~u : (u | 0x80000000u);
}
__device__ __forceinline__ float dec_f(unsigned e) {
  unsigned u = (e & 0x80000000u) ? (e ^ 0x80000000u) : ~e;
  return __uint_as_float(u);
}
__device__ __forceinline__ ushort f16_bits(float x) {
  _Float16 h = (_Float16)x;               // RNE convert
  return __builtin_bit_cast(ushort, h);
}
__device__ __forceinline__ void split_f16(float x, ushort& h, ushort& l) {
  _Float16 hf = (_Float16)x;
  float r = x - (float)hf;
  h = __builtin_bit_cast(ushort, hf);
  l = __builtin_bit_cast(ushort, (_Float16)r);
}

// async global->LDS, 16B per lane; LDS dest wave-uniform, lane*16 placement.
__device__ __forceinline__ void gl_lds16(const ushort* g, ushort* l) {
  using gas_t = const __attribute__((address_space(1))) uint32_t*;
  using las_t = __attribute__((address_space(3))) uint32_t*;
  __builtin_amdgcn_global_load_lds((gas_t)(uintptr_t)g,
                                   (las_t)(unsigned)(uintptr_t)l, 16, 0, 0);
}

// ---------- decompose fp32 -> f16 hi plane only ----------
__global__ void dec1_k(const float4* __restrict__ x, uint2* __restrict__ h, int n4) {
  int i = blockIdx.x * blockDim.x + threadIdx.x;
  const int stride = gridDim.x * blockDim.x;
  for (; i < n4; i += stride) {
    float4 v = x[i];
    uint2 hw;
    hw.x = (unsigned)f16_bits(v.x) | ((unsigned)f16_bits(v.y) << 16);
    hw.y = (unsigned)f16_bits(v.z) | ((unsigned)f16_bits(v.w) << 16);
    h[i] = hw;
  }
}

// ---------- transpose + decompose U (scaled by 2048 to keep U_lo in f16 normal range) ----------
__global__ void transdec_k(const float* __restrict__ U,
                           ushort* __restrict__ UTh, ushort* __restrict__ UTl) {
  __shared__ float t[32][33];
  const int tx = threadIdx.x, ty = threadIdx.y;
  const int e0 = blockIdx.x * 32, d0 = blockIdx.y * 32;
#pragma unroll
  for (int r = 0; r < 4; ++r)
    t[ty + r * 8][tx] = U[(size_t)(d0 + ty + r * 8) * D_ + e0 + tx];
  __syncthreads();
#pragma unroll
  for (int r = 0; r < 4; ++r) {
    int e = ty + r * 8;
    ushort h, l;
    split_f16(t[tx][e] * 2048.0f, h, l);
    UTh[(size_t)(e0 + e) * D_ + d0 + tx] = h;
    UTl[(size_t)(e0 + e) * D_ + d0 + tx] = l;
  }
}

// ============ 256x256 tile GEMM cores: 8 waves (2x4), f16, BK=32 ============
// Rows of 32 ushorts = 4 x 16B slots; swizzle slot' = slot ^ ((row>>1)&3),
// applied on the GLOBAL source at stage time and on the ds_read address.
struct CoreCtx {
  int w, lane, ln, kq, wm, wn, ko;
  size_t soA;   // per-lane staging offset (ushorts) into a plane panel
};

__device__ __forceinline__ CoreCtx make_ctx() {
  CoreCtx c;
  const int tid = threadIdx.x;
  c.w = tid >> 6; c.lane = tid & 63;
  c.ln = c.lane & 15; c.kq = c.lane >> 4;
  c.wm = c.w >> 2; c.wn = c.w & 3;
  c.ko = (c.kq ^ ((c.ln >> 1) & 3)) * 8;
  const int srow = c.lane >> 2;
  const int sslot = (c.lane & 3) ^ ((c.lane >> 3) & 3);
  c.soA = (size_t)(c.w * 32 + srow) * D_ + sslot * 8;
  return c;
}

// stage one 256x32 plane: wave w covers rows [w*32, w*32+32), 2 gl_lds
__device__ __forceinline__ void stage_plane(const ushort* src, ushort* dstbase,
                                            const CoreCtx& c, int k0) {
  const size_t a0 = c.soA + k0, a1 = a0 + (size_t)16 * D_;
  ushort* d0 = dstbase + c.w * 1024;
  gl_lds16(src + a0, d0);
  gl_lds16(src + a1, d0 + 512);
}

#define VMCNT(n) asm volatile("s_waitcnt vmcnt(" #n ")" ::: "memory")
#define BARRIER() do { asm volatile("" ::: "memory"); \
                       __builtin_amdgcn_s_barrier();  \
                       asm volatile("" ::: "memory"); } while (0)

// read the 12 fragment b128s of one (A|B) tile buffer
#define READ_FRAGS(cb, Aa, Bb)                                   \
  do {                                                           \
    _Pragma("unroll")                                            \
    for (int n_ = 0; n_ < 4; ++n_) {                             \
      const int r_ = c.wn * 64 + n_ * 16 + c.ln;                 \
      Bb[n_] = *(const f16x8*)&(cb)[8192 + r_ * 32 + c.ko];      \
    }                                                            \
    _Pragma("unroll")                                            \
    for (int m_ = 0; m_ < 8; ++m_) {                             \
      const int r_ = c.wm * 128 + m_ * 16 + c.ln;                \
      Aa[m_] = *(const f16x8*)&(cb)[r_ * 32 + c.ko];             \
    }                                                            \
  } while (0)

#define MFMA32(Aa, Bb)                                                        \
  do {                                                                       \
    __builtin_amdgcn_s_setprio(1);                                           \
    _Pragma("unroll")                                                        \
    for (int m_ = 0; m_ < 8; ++m_)                                           \
      _Pragma("unroll")                                                      \
      for (int n_ = 0; n_ < 4; ++n_)                                         \
        acc[m_][n_] = __builtin_amdgcn_mfma_f32_16x16x32_f16(Aa[m_], Bb[n_], \
                                                             acc[m_][n_], 0, 0, 0); \
    __builtin_amdgcn_s_setprio(0);                                           \
  } while (0)

// --- gemm1 core: 3 planes (Ah | Bh | Bl), BK=32, 2-phase counted-vmcnt (r8-proven) ---
__device__ __forceinline__ void core_loop3(const CoreCtx& c,
    const ushort* Ah, const ushort* Bh, const ushort* Bl,
    ushort* lbuf, f32x4 acc[8][4])
{
  stage_plane(Ah, lbuf,         c, 0);
  stage_plane(Bh, lbuf + 8192,  c, 0);
  stage_plane(Bl, lbuf + 16384, c, 0);

  for (int t = 0; t < 32; ++t) {
    const ushort* cb = lbuf + (t & 1) * 24576;
    ushort* nb = lbuf + ((t + 1) & 1) * 24576;
    const int kn = (t + 1) * 32;
    const bool pf = (t < 31);
    f16x8 a[8], bh4[4], bl4[4];

    // ---- phase 1: hh ----
    VMCNT(2);                       // Ah,Bh(t) landed; Bl(t) may fly
    BARRIER();
#pragma unroll
    for (int n = 0; n < 4; ++n) {
      const int r = c.wn * 64 + n * 16 + c.ln;
      bh4[n] = *(const f16x8*)&cb[8192 + r * 32 + c.ko];
    }
#pragma unroll
    for (int m = 0; m < 8; ++m) {
      const int r = c.wm * 128 + m * 16 + c.ln;
      a[m] = *(const f16x8*)&cb[r * 32 + c.ko];
    }
    if (pf) { stage_plane(Ah, nb, c, kn); stage_plane(Bh, nb + 8192, c, kn); }
    __builtin_amdgcn_s_setprio(1);
#pragma unroll
    for (int m = 0; m < 8; ++m)
#pragma unroll
      for (int n = 0; n < 4; ++n)
        acc[m][n] = __builtin_amdgcn_mfma_f32_16x16x32_f16(a[m], bh4[n], acc[m][n], 0, 0, 0);
    __builtin_amdgcn_s_setprio(0);

    // ---- phase 2: A_hi x B_lo ----
    if (pf) { VMCNT(4); } else { VMCNT(0); }   // Bl(t) landed
    BARRIER();
#pragma unroll
    for (int n = 0; n < 4; ++n) {
      const int r = c.wn * 64 + n * 16 + c.ln;
      bl4[n] = *(const f16x8*)&cb[16384 + r * 32 + c.ko];
    }
    if (pf) stage_plane(Bl, nb + 16384, c, kn);
    __builtin_amdgcn_s_setprio(1);
#pragma unroll
    for (int m = 0; m < 8; ++m)
#pragma unroll
      for (int n = 0; n < 4; ++n)
        acc[m][n] = __builtin_amdgcn_mfma_f32_16x16x32_f16(a[m], bl4[n], acc[m][n], 0, 0, 0);
    __builtin_amdgcn_s_setprio(0);
  }
}

// ---------- GEMM1: Y = (x1 @ (U*2048)) / 2048 -> f16 hi plane ----------
__global__ __launch_bounds__(512, 2) void gemm1_k(
    const ushort* __restrict__ x1h,
    const ushort* __restrict__ UTh, const ushort* __restrict__ UTl,
    ushort* __restrict__ Yh)
{
  __shared__ __attribute__((aligned(16))) ushort lbuf[65536];
  const int z = blockIdx.z;
  const int orig = blockIdx.x;                 // 0..31
  const int xc = orig & 7, j = orig >> 3;      // j 0..3
  const int bx = (xc & 3) * 2 + (j & 1);       // 0..7
  const int by = (xc >> 2) * 2 + (j >> 1);     // 0..3

  const size_t zb = (size_t)z * (L_ * D_);
  const ushort* Ah = x1h + zb + (size_t)bx * 256 * D_;
  const ushort* Bh = UTh + (size_t)by * 256 * D_;
  const ushort* Bl = UTl + (size_t)by * 256 * D_;

  CoreCtx c = make_ctx();
  f32x4 acc[8][4];
#pragma unroll
  for (int m = 0; m < 8; ++m)
#pragma unroll
    for (int n = 0; n < 4; ++n) acc[m][n] = (f32x4){0.f, 0.f, 0.f, 0.f};

  core_loop3(c, Ah, Bh, Bl, lbuf, acc);

  __syncthreads();   // lbuf reused below

  // epilogue: unscale by 2^-11, convert to f16, LDS-coalesce, write Yh.
  ushort* ep = lbuf + c.w * 8192;
  const int grow = bx * 256 + c.wm * 128;
  const int gcol = by * 256 + c.wn * 64;
#pragma unroll
  for (int m = 0; m < 8; ++m)
#pragma unroll
    for (int n = 0; n < 4; ++n)
#pragma unroll
      for (int r2 = 0; r2 < 4; ++r2) {
        float v = acc[m][n][r2] * 4.8828125e-4f;   // 1/2048
        ep[(m * 16 + c.kq * 4 + r2) * 64 + n * 16 + c.ln] = f16_bits(v);
      }
#pragma unroll
  for (int q = 0; q < 16; ++q) {
    const int chunk = q * 64 + c.lane;
    const int row = chunk >> 3, c8 = (chunk & 7) * 8;
    f16x8 v = *(const f16x8*)&ep[row * 64 + c8];
    *(f16x8*)&Yh[zb + (size_t)(grow + row) * D_ + gcol + c8] = v;
  }
}

// ---------- GEMM2: M = Yh @ x2h^T, BK=32, quad-buffer, skewed frag reads ----------
// Per tile t: stage(t+2) | vmcnt(4) | barrier | ds_read f(t+1) | MFMA f(t).
// Fragment reads overlap the MFMA cluster (results consumed next tile);
// quad-buffer (4 x 32KB) gives the 2-tile write-after-read distance.
__global__ __launch_bounds__(512, 2) void gemm2_k(
    const ushort* __restrict__ Yh,
    const ushort* __restrict__ x2h,
    unsigned* __restrict__ rmxg, unsigned* __restrict__ cmxg)
{
  __shared__ __attribute__((aligned(16))) ushort lbuf[65536];  // 4 x 16384 (A|B)
  const int z = blockIdx.z;
  const int orig = blockIdx.x;                 // 0..63
  const int xc = orig & 7, j = orig >> 3;      // j 0..7
  const int bx = (xc & 3) * 2 + (j & 1);       // 0..7
  const int by = (xc >> 2) * 4 + (j >> 1);     // 0..7

  const size_t zb = (size_t)z * (L_ * D_);
  const ushort* Ah = Yh + zb + (size_t)bx * 256 * D_;
  const ushort* Bh = x2h + zb + (size_t)by * 256 * D_;

  CoreCtx c = make_ctx();
  f32x4 acc[8][4];
#pragma unroll
  for (int m = 0; m < 8; ++m)
#pragma unroll
    for (int n = 0; n < 4; ++n) acc[m][n] = (f32x4){0.f, 0.f, 0.f, 0.f};

  ushort* q0 = lbuf;              // tile t
  ushort* q1 = lbuf + 16384;      // tile t+1
  ushort* q2 = lbuf + 32768;      // tile t+2 (staging dest)
  ushort* q3 = lbuf + 49152;      // tile t+3 (staging dest next tile)

  f16x8 aA[8], bA[4], aB[8], bB[4];

  // prologue: stage tiles 0,1; publish tile 0; read f(0)
  stage_plane(Ah, q0, c, 0);  stage_plane(Bh, q0 + 8192, c, 0);
  stage_plane(Ah, q1, c, 32); stage_plane(Bh, q1 + 8192, c, 32);
  VMCNT(4);                     // tile 0 landed (tile 1's 4 in flight)
  BARRIER();
  READ_FRAGS(q0, aA, bA);
  __builtin_amdgcn_sched_barrier(0);

  for (int tp = 0; tp < 15; ++tp) {
    const int t0 = 2 * tp;
    // ---- tile t0: consume A, fill B ----
    stage_plane(Ah, q2, c, (t0 + 2) * 32);
    stage_plane(Bh, q2 + 8192, c, (t0 + 2) * 32);
    VMCNT(4);                  // own stage(t0+1) landed; stage(t0+2) in flight
    BARRIER();                 // all waves' stage(t0+1) landed
    READ_FRAGS(q1, aB, bB);    // f(t0+1)
    __builtin_amdgcn_sched_barrier(0);
    MFMA32(aA, bA);            // f(t0)
    // ---- tile t0+1: consume B, fill A ----
    stage_plane(Ah, q3, c, (t0 + 3) * 32);
    stage_plane(Bh, q3 + 8192, c, (t0 + 3) * 32);
    VMCNT(4);
    BARRIER();
    READ_FRAGS(q2, aA, bA);    // f(t0+2)
    __builtin_amdgcn_sched_barrier(0);
    MFMA32(aB, bB);            // f(t0+1)
    // rotate buffers by 2
    ushort* r0 = q0; ushort* r1 = q1;
    q0 = q2; q1 = q3; q2 = r0; q3 = r1;
  }
  // tile 30: consume A, fill B with f(31)
  VMCNT(0);                    // stage(31) landed
  BARRIER();
  READ_FRAGS(q1, aB, bB);
  __builtin_amdgcn_sched_barrier(0);
  MFMA32(aA, bA);
  // tile 31: consume B
  MFMA32(aB, bB);

  // epilogue: tile row/col max -> LDS atomics -> global atomics
  __syncthreads();
  unsigned* red = (unsigned*)lbuf;   // [0..255]=row max, [256..511]=col max
  const int tid = threadIdx.x;
  red[tid] = 0u;
  __syncthreads();

#pragma unroll
  for (int m = 0; m < 8; ++m) {
#pragma unroll
    for (int r2 = 0; r2 < 4; ++r2) {
      float v = fmaxf(fmaxf(acc[m][0][r2], acc[m][1][r2]),
                      fmaxf(acc[m][2][r2], acc[m][3][r2]));
#pragma unroll
      for (int s = 1; s < 16; s <<= 1) v = fmaxf(v, __shfl_xor(v, s));
      if (c.ln == 0) atomicMax(&red[c.wm * 128 + m * 16 + c.kq * 4 + r2], enc_f(v));
    }
  }
#pragma unroll
  for (int n = 0; n < 4; ++n) {
    float v = -3.4e38f;
#pragma unroll
    for (int m = 0; m < 8; ++m)
#pragma unroll
      for (int r2 = 0; r2 < 4; ++r2) v = fmaxf(v, acc[m][n][r2]);
    v = fmaxf(v, __shfl_xor(v, 16));
    v = fmaxf(v, __shfl_xor(v, 32));
    if (c.kq == 0) atomicMax(&red[256 + c.wn * 64 + n * 16 + c.ln], enc_f(v));
  }
  __syncthreads();
  if (tid < 256) atomicMax(&rmxg[(size_t)z * L_ + bx * 256 + tid], red[tid]);
  else           atomicMax(&cmxg[(size_t)z * L_ + by * 256 + (tid - 256)], red[tid]);
}

// ---------- softmax over 2048 encoded maxima per batch ----------
__global__ void softmax_k(const unsigned* __restrict__ enc, float* __restrict__ w) {
  __shared__ float red[256];
  const int b = blockIdx.x, tid = threadIdx.x;
  const unsigned* e = enc + (size_t)b * L_;
  float* wb = w + (size_t)b * L_;
  float vals[8];
  float lmax = -3.4e38f;
#pragma unroll
  for (int q = 0; q < 8; ++q) {
    float f = dec_f(e[q * 256 + tid]);
    vals[q] = f;
    lmax = fmaxf(lmax, f);
  }
  red[tid] = lmax; __syncthreads();
  for (int s = 128; s > 0; s >>= 1) {
    if (tid < s) red[tid] = fmaxf(red[tid], red[tid + s]);
    __syncthreads();
  }
  const float mx = red[0];
  __syncthreads();
  float lsum = 0.f;
#pragma unroll
  for (int q = 0; q < 8; ++q) { vals[q] = expf(vals[q] - mx); lsum += vals[q]; }
  red[tid] = lsum; __syncthreads();
  for (int s = 128; s > 0; s >>= 1) {
    if (tid < s) red[tid] += red[tid + s];
    __syncthreads();
  }
  const float inv = 1.f / red[0];
#pragma unroll
  for (int q = 0; q < 8; ++q) wb[q * 256 + tid] = vals[q] * inv;
}

// ---------- weighted sum (f16 input planes) ----------
__global__ void wsum_k(const float* __restrict__ w, const ushort* __restrict__ xh,
                       float* __restrict__ out) {
  __shared__ float ws[256];
  const int tid = threadIdx.x;
  const int b = blockIdx.y;
  const int i0 = blockIdx.x * 256;
  ws[tid] = w[(size_t)b * L_ + i0 + tid];
  __syncthreads();
  const int d0 = tid * 4;
  const ushort* xb = xh + ((size_t)b * L_ + i0) * D_ + d0;
  float4 acc = {0.f, 0.f, 0.f, 0.f};
  for (int i = 0; i < 256; ++i) {
    ushort4 v = *(const ushort4*)(xb + (size_t)i * D_);
    float wi = ws[i];
    acc.x = fmaf(wi, (float)__builtin_bit_cast(_Float16, v.x), acc.x);
    acc.y = fmaf(wi, (float)__builtin_bit_cast(_Float16, v.y), acc.y);
    acc.z = fmaf(wi, (float)__builtin_bit_cast(_Float16, v.z), acc.z);
    acc.w = fmaf(wi, (float)__builtin_bit_cast(_Float16, v.w), acc.w);
  }
  float* o = out + (size_t)b * D_ + d0;
  atomicAdd(o + 0, acc.x);
  atomicAdd(o + 1, acc.y);
  atomicAdd(o + 2, acc.z);
  atomicAdd(o + 3, acc.w);
}

extern "C" void kernel_launch(void* const* d_in, const int* in_sizes, int n_in,
                              void* d_out, int out_size, void* d_ws, size_t ws_size,
                              hipStream_t stream) {
  (void)in_sizes; (void)n_in; (void)out_size;
  const float* x1 = (const float*)d_in[0];
  const float* x2 = (const float*)d_in[1];
  const float* U  = (const float*)d_in[2];
  float* out = (float*)d_out;

  // workspace layout
  char* p = (char*)d_ws;
  ushort* UTh = (ushort*)p; p += (size_t)D_ * D_ * 2;
  ushort* UTl = (ushort*)p; p += (size_t)D_ * D_ * 2;
  unsigned* rowmax = (unsigned*)p; p += (size_t)B_ * L_ * 4;
  unsigned* colmax = (unsigned*)p; p += (size_t)B_ * L_ * 4;
  float* w1 = (float*)p; p += (size_t)B_ * L_ * 4;
  float* w2 = (float*)p; p += (size_t)B_ * L_ * 4;
  const size_t fixed = (size_t)(p - (char*)d_ws);
  const size_t perB = (size_t)3 * L_ * D_ * 2;    // 3 f16 planes per batch = 12MB
  int G = 1;
  if (ws_size > fixed) {
    size_t g = (ws_size - fixed) / perB;
    G = g < 1 ? 1 : (g > (size_t)B_ ? B_ : (int)g);
  }
  ushort* x1h = (ushort*)p;
  ushort* x2h = x1h + (size_t)G * L_ * D_;
  ushort* Yh  = x2h + (size_t)G * L_ * D_;

  hipMemsetAsync(d_out, 0, (size_t)2 * B_ * D_ * 4, stream);
  hipMemsetAsync(rowmax, 0, (size_t)2 * B_ * L_ * 4, stream); // rowmax+colmax contiguous

  transdec_k<<<dim3(32, 32), dim3(32, 8), 0, stream>>>(U, UTh, UTl);

  for (int g0 = 0; g0 < B_; g0 += G) {
    const int Gc = (B_ - g0) < G ? (B_ - g0) : G;
    const int n4 = Gc * (L_ * D_ / 4);
    dec1_k<<<dim3(1024), 256, 0, stream>>>(
        (const float4*)(x1 + (size_t)g0 * L_ * D_), (uint2*)x1h, n4);
    dec1_k<<<dim3(1024), 256, 0, stream>>>(
        (const float4*)(x2 + (size_t)g0 * L_ * D_), (uint2*)x2h, n4);
    gemm1_k<<<dim3(32, 1, Gc), 512, 0, stream>>>(x1h, UTh, UTl, Yh);
    gemm2_k<<<dim3(64, 1, Gc), 512, 0, stream>>>(Yh, x2h,
        rowmax + (size_t)g0 * L_, colmax + (size_t)g0 * L_);
    // per-group softmax + weighted sums (f16 planes are group-local)
    softmax_k<<<dim3(Gc), 256, 0, stream>>>(rowmax + (size_t)g0 * L_,
                                            w1 + (size_t)g0 * L_);
    softmax_k<<<dim3(Gc), 256, 0, stream>>>(colmax + (size_t)g0 * L_,
                                            w2 + (size_t)g0 * L_);
    wsum_k<<<dim3(8, Gc), 256, 0, stream>>>(w1 + (size_t)g0 * L_, x1h,
                                            out + (size_t)g0 * D_);
    wsum_k<<<dim3(8, Gc), 256, 0, stream>>>(w2 + (size_t)g0 * L_, x2h,
                                            out + (size_t)(B_ + g0) * D_);
  }
}

// Round 13
// 720.470 us; speedup vs baseline: 1.6447x; 1.0058x over previous
//
#include <hip/hip_runtime.h>
#include <hip/hip_bf16.h>
#include <stdint.h>

#define B_  32
#define L_  2048   // L1 == L2
#define D_  1024   // D1 == D2

typedef __attribute__((ext_vector_type(8))) _Float16 f16x8;
typedef __attribute__((ext_vector_type(4))) float f32x4;

// ---------- helpers ----------
__device__ __forceinline__ unsigned enc_f(float x) {
  unsigned u = __float_as_uint(x);
  return (u & 0x80000000u) ? ~u : (u | 0x80000000u);
}
__device__ __forceinline__ float dec_f(unsigned e) {
  unsigned u = (e & 0x80000000u) ? (e ^ 0x80000000u) : ~e;
  return __uint_as_float(u);
}
__device__ __forceinline__ ushort f16_bits(float x) {
  _Float16 h = (_Float16)x;               // RNE convert
  return __builtin_bit_cast(ushort, h);
}
__device__ __forceinline__ void split_f16(float x, ushort& h, ushort& l) {
  _Float16 hf = (_Float16)x;
  float r = x - (float)hf;
  h = __builtin_bit_cast(ushort, hf);
  l = __builtin_bit_cast(ushort, (_Float16)r);
}

// async global->LDS, 16B per lane; LDS dest wave-uniform, lane*16 placement.
__device__ __forceinline__ void gl_lds16(const ushort* g, ushort* l) {
  using gas_t = const __attribute__((address_space(1))) uint32_t*;
  using las_t = __attribute__((address_space(3))) uint32_t*;
  __builtin_amdgcn_global_load_lds((gas_t)(uintptr_t)g,
                                   (las_t)(unsigned)(uintptr_t)l, 16, 0, 0);
}

// ---------- decompose fp32 -> f16 hi plane only ----------
__global__ void dec1_k(const float4* __restrict__ x, uint2* __restrict__ h, int n4) {
  int i = blockIdx.x * blockDim.x + threadIdx.x;
  const int stride = gridDim.x * blockDim.x;
  for (; i < n4; i += stride) {
    float4 v = x[i];
    uint2 hw;
    hw.x = (unsigned)f16_bits(v.x) | ((unsigned)f16_bits(v.y) << 16);
    hw.y = (unsigned)f16_bits(v.z) | ((unsigned)f16_bits(v.w) << 16);
    h[i] = hw;
  }
}

// ---------- transpose + decompose U (scaled by 2048 to keep U_lo in f16 normal range) ----------
__global__ void transdec_k(const float* __restrict__ U,
                           ushort* __restrict__ UTh, ushort* __restrict__ UTl) {
  __shared__ float t[32][33];
  const int tx = threadIdx.x, ty = threadIdx.y;
  const int e0 = blockIdx.x * 32, d0 = blockIdx.y * 32;
#pragma unroll
  for (int r = 0; r < 4; ++r)
    t[ty + r * 8][tx] = U[(size_t)(d0 + ty + r * 8) * D_ + e0 + tx];
  __syncthreads();
#pragma unroll
  for (int r = 0; r < 4; ++r) {
    int e = ty + r * 8;
    ushort h, l;
    split_f16(t[tx][e] * 2048.0f, h, l);
    UTh[(size_t)(e0 + e) * D_ + d0 + tx] = h;
    UTl[(size_t)(e0 + e) * D_ + d0 + tx] = l;
  }
}

// ============ 256x256 tile GEMM cores: 8 waves (2x4), f16 ============
struct CoreCtx {
  int w, lane, ln, kq, wm, wn, ko;
  size_t soA;   // BK=32 staging offset (gemm1)
};

__device__ __forceinline__ CoreCtx make_ctx() {
  CoreCtx c;
  const int tid = threadIdx.x;
  c.w = tid >> 6; c.lane = tid & 63;
  c.ln = c.lane & 15; c.kq = c.lane >> 4;
  c.wm = c.w >> 2; c.wn = c.w & 3;
  c.ko = (c.kq ^ ((c.ln >> 1) & 3)) * 8;
  const int srow = c.lane >> 2;
  const int sslot = (c.lane & 3) ^ ((c.lane >> 3) & 3);
  c.soA = (size_t)(c.w * 32 + srow) * D_ + sslot * 8;
  return c;
}

// stage one 256x32 plane (BK=32): wave w covers rows [w*32, w*32+32), 2 gl_lds
__device__ __forceinline__ void stage_plane(const ushort* src, ushort* dstbase,
                                            const CoreCtx& c, int k0) {
  const size_t a0 = c.soA + k0, a1 = a0 + (size_t)16 * D_;
  ushort* d0 = dstbase + c.w * 1024;
  gl_lds16(src + a0, d0);
  gl_lds16(src + a1, d0 + 512);
}

#define VMCNT(n) asm volatile("s_waitcnt vmcnt(" #n ")" ::: "memory")
#define BARRIER() do { asm volatile("" ::: "memory"); \
                       __builtin_amdgcn_s_barrier();  \
                       asm volatile("" ::: "memory"); } while (0)

// --- gemm1 core: 3 planes (Ah | Bh | Bl), BK=32, 2-phase counted-vmcnt (r8-proven) ---
__device__ __forceinline__ void core_loop3(const CoreCtx& c,
    const ushort* Ah, const ushort* Bh, const ushort* Bl,
    ushort* lbuf, f32x4 acc[8][4])
{
  stage_plane(Ah, lbuf,         c, 0);
  stage_plane(Bh, lbuf + 8192,  c, 0);
  stage_plane(Bl, lbuf + 16384, c, 0);

  for (int t = 0; t < 32; ++t) {
    const ushort* cb = lbuf + (t & 1) * 24576;
    ushort* nb = lbuf + ((t + 1) & 1) * 24576;
    const int kn = (t + 1) * 32;
    const bool pf = (t < 31);
    f16x8 a[8], bh4[4], bl4[4];

    // ---- phase 1: hh ----
    VMCNT(2);                       // Ah,Bh(t) landed; Bl(t) may fly
    BARRIER();
#pragma unroll
    for (int n = 0; n < 4; ++n) {
      const int r = c.wn * 64 + n * 16 + c.ln;
      bh4[n] = *(const f16x8*)&cb[8192 + r * 32 + c.ko];
    }
#pragma unroll
    for (int m = 0; m < 8; ++m) {
      const int r = c.wm * 128 + m * 16 + c.ln;
      a[m] = *(const f16x8*)&cb[r * 32 + c.ko];
    }
    if (pf) { stage_plane(Ah, nb, c, kn); stage_plane(Bh, nb + 8192, c, kn); }
    __builtin_amdgcn_s_setprio(1);
#pragma unroll
    for (int m = 0; m < 8; ++m)
#pragma unroll
      for (int n = 0; n < 4; ++n)
        acc[m][n] = __builtin_amdgcn_mfma_f32_16x16x32_f16(a[m], bh4[n], acc[m][n], 0, 0, 0);
    __builtin_amdgcn_s_setprio(0);

    // ---- phase 2: A_hi x B_lo ----
    if (pf) { VMCNT(4); } else { VMCNT(0); }   // Bl(t) landed
    BARRIER();
#pragma unroll
    for (int n = 0; n < 4; ++n) {
      const int r = c.wn * 64 + n * 16 + c.ln;
      bl4[n] = *(const f16x8*)&cb[16384 + r * 32 + c.ko];
    }
    if (pf) stage_plane(Bl, nb + 16384, c, kn);
    __builtin_amdgcn_s_setprio(1);
#pragma unroll
    for (int m = 0; m < 8; ++m)
#pragma unroll
      for (int n = 0; n < 4; ++n)
        acc[m][n] = __builtin_amdgcn_mfma_f32_16x16x32_f16(a[m], bl4[n], acc[m][n], 0, 0, 0);
    __builtin_amdgcn_s_setprio(0);
  }
}

// ---------- GEMM1: Y = (x1 @ (U*2048)) / 2048 -> f16 hi plane ----------
__global__ __launch_bounds__(512, 2) void gemm1_k(
    const ushort* __restrict__ x1h,
    const ushort* __restrict__ UTh, const ushort* __restrict__ UTl,
    ushort* __restrict__ Yh)
{
  __shared__ __attribute__((aligned(16))) ushort lbuf[65536];
  const int z = blockIdx.z;
  const int orig = blockIdx.x;                 // 0..31
  const int xc = orig & 7, j = orig >> 3;      // j 0..3
  const int bx = (xc & 3) * 2 + (j & 1);       // 0..7
  const int by = (xc >> 2) * 2 + (j >> 1);     // 0..3

  const size_t zb = (size_t)z * (L_ * D_);
  const ushort* Ah = x1h + zb + (size_t)bx * 256 * D_;
  const ushort* Bh = UTh + (size_t)by * 256 * D_;
  const ushort* Bl = UTl + (size_t)by * 256 * D_;

  CoreCtx c = make_ctx();
  f32x4 acc[8][4];
#pragma unroll
  for (int m = 0; m < 8; ++m)
#pragma unroll
    for (int n = 0; n < 4; ++n) acc[m][n] = (f32x4){0.f, 0.f, 0.f, 0.f};

  core_loop3(c, Ah, Bh, Bl, lbuf, acc);

  __syncthreads();   // lbuf reused below

  // epilogue: unscale by 2^-11, convert to f16, LDS-coalesce, write Yh.
  ushort* ep = lbuf + c.w * 8192;
  const int grow = bx * 256 + c.wm * 128;
  const int gcol = by * 256 + c.wn * 64;
#pragma unroll
  for (int m = 0; m < 8; ++m)
#pragma unroll
    for (int n = 0; n < 4; ++n)
#pragma unroll
      for (int r2 = 0; r2 < 4; ++r2) {
        float v = acc[m][n][r2] * 4.8828125e-4f;   // 1/2048
        ep[(m * 16 + c.kq * 4 + r2) * 64 + n * 16 + c.ln] = f16_bits(v);
      }
#pragma unroll
  for (int q = 0; q < 16; ++q) {
    const int chunk = q * 64 + c.lane;
    const int row = chunk >> 3, c8 = (chunk & 7) * 8;
    f16x8 v = *(const f16x8*)&ep[row * 64 + c8];
    *(f16x8*)&Yh[zb + (size_t)(grow + row) * D_ + gcol + c8] = v;
  }
}

// ---------- GEMM2: M = Yh @ x2h^T, BK=64, 4-phase m201-style core ----------
// LDS per buffer (32768 ushorts = 64KB): Ahalf0 | Ahalf1 | Bhalf0 | Bhalf1
// (each 128 rows x 64 ushorts). Rows of 64 ushorts = 8 x 16B slots; swizzle
// phys_slot = slot ^ (row&7) (r11-verified conflict-free), applied on the
// GLOBAL source at stage time and on the ds_read address.
// Per tile t: 4 phases {ds_read frags -> stage half(t+1) -> 16 MFMA ->
// sched_barrier}; ONE vmcnt(0)+s_barrier per tile. Phases read fresh register
// sets (WAR distance >= 2 phases). Stage halves at phases 0,1,2 (2+2+4 loads)
// so the newest load has ~2 phases to land before the tile-end drain.
__global__ __launch_bounds__(512, 2) void gemm2_k(
    const ushort* __restrict__ Yh,
    const ushort* __restrict__ x2h,
    unsigned* __restrict__ rmxg, unsigned* __restrict__ cmxg)
{
  __shared__ __attribute__((aligned(16))) ushort lbuf[65536];  // 2 x 32768
  const int z = blockIdx.z;
  const int orig = blockIdx.x;                 // 0..63
  const int xc = orig & 7, j = orig >> 3;      // j 0..7
  const int bx = (xc & 3) * 2 + (j & 1);       // 0..7
  const int by = (xc >> 2) * 4 + (j >> 1);     // 0..7

  const size_t zb = (size_t)z * (L_ * D_);
  const ushort* Ap = Yh + zb + (size_t)bx * 256 * D_;
  const ushort* Bp = x2h + zb + (size_t)by * 256 * D_;

  const int tid = threadIdx.x;
  const int w = tid >> 6, lane = tid & 63;
  const int ln = lane & 15, kq = lane >> 4;
  const int wm = w >> 2, wn = w & 3;
  const int ko0 = ((kq)     ^ (ln & 7)) * 8;   // ks=0 slot (swizzled), ushorts
  const int ko1 = ((4 + kq) ^ (ln & 7)) * 8;   // ks=1
  const int srow8 = lane >> 3;
  const int sslot8 = (lane & 7) ^ srow8;
  const size_t sOff = (size_t)(w * 16 + srow8) * D_ + sslot8 * 8;

  f32x4 acc[8][4];
#pragma unroll
  for (int m = 0; m < 8; ++m)
#pragma unroll
    for (int n = 0; n < 4; ++n) acc[m][n] = (f32x4){0.f, 0.f, 0.f, 0.f};

  // staging sources (half h) and LDS half bases
  const ushort* srcH0 = Ap;
  const ushort* srcH1 = Ap + (size_t)128 * D_;
  const ushort* srcH2 = Bp;
  const ushort* srcH3 = Bp + (size_t)128 * D_;

#define STAGE_H(nb, hbase, srcp, kt)                                   \
  do {                                                                 \
    const size_t a_ = sOff + (size_t)(kt) * 64;                        \
    ushort* d_ = (nb) + (hbase) + w * 1024;                            \
    gl_lds16((srcp) + a_, d_);                                         \
    gl_lds16((srcp) + a_ + (size_t)8 * D_, d_ + 512);                  \
  } while (0)

  // prologue: stage all 4 halves of tile 0
  STAGE_H(lbuf, 0,     srcH0, 0);
  STAGE_H(lbuf, 8192,  srcH1, 0);
  STAGE_H(lbuf, 16384, srcH2, 0);
  STAGE_H(lbuf, 24576, srcH3, 0);
  VMCNT(0);
  BARRIER();

  for (int t = 0; t < 16; ++t) {
    const ushort* cb = lbuf + (t & 1) * 32768;
    ushort* nb = lbuf + ((t + 1) & 1) * 32768;
    const bool pf = (t < 15);
    const int kn = t + 1;
    const ushort* aB = cb + wm * 8192;                 // this wave's A half
    const ushort* bB = cb + 16384 + (wn >> 1) * 8192;  // this wave's B half
    const int rB = (wn & 1) * 64;

    f16x8 aX[4], aY[4], b0[4], b1[4];

    // ---- phase 0: quadrant (mq=0, ks=0); stage A-half0(t+1) ----
#pragma unroll
    for (int n = 0; n < 4; ++n)
      b0[n] = *(const f16x8*)&bB[(rB + n * 16 + ln) * 64 + ko0];
#pragma unroll
    for (int m = 0; m < 4; ++m)
      aX[m] = *(const f16x8*)&aB[(m * 16 + ln) * 64 + ko0];
    if (pf) STAGE_H(nb, 0, srcH0, kn);
    __builtin_amdgcn_s_setprio(1);
#pragma unroll
    for (int m = 0; m < 4; ++m)
#pragma unroll
      for (int n = 0; n < 4; ++n)
        acc[m][n] = __builtin_amdgcn_mfma_f32_16x16x32_f16(aX[m], b0[n], acc[m][n], 0, 0, 0);
    __builtin_amdgcn_s_setprio(0);
    __builtin_amdgcn_sched_barrier(0);

    // ---- phase 1: quadrant (mq=1, ks=0); stage A-half1(t+1) ----
#pragma unroll
    for (int m = 0; m < 4; ++m)
      aY[m] = *(const f16x8*)&aB[((64 + m * 16 + ln)) * 64 + ko0];
    if (pf) STAGE_H(nb, 8192, srcH1, kn);
    __builtin_amdgcn_s_setprio(1);
#pragma unroll
    for (int m = 0; m < 4; ++m)
#pragma unroll
      for (int n = 0; n < 4; ++n)
        acc[4 + m][n] = __builtin_amdgcn_mfma_f32_16x16x32_f16(aY[m], b0[n], acc[4 + m][n], 0, 0, 0);
    __builtin_amdgcn_s_setprio(0);
    __builtin_amdgcn_sched_barrier(0);

    // ---- phase 2: quadrant (mq=0, ks=1); stage B-half0+B-half1(t+1) ----
#pragma unroll
    for (int n = 0; n < 4; ++n)
      b1[n] = *(const f16x8*)&bB[(rB + n * 16 + ln) * 64 + ko1];
#pragma unroll
    for (int m = 0; m < 4; ++m)
      aX[m] = *(const f16x8*)&aB[(m * 16 + ln) * 64 + ko1];
    if (pf) { STAGE_H(nb, 16384, srcH2, kn); STAGE_H(nb, 24576, srcH3, kn); }
    __builtin_amdgcn_s_setprio(1);
#pragma unroll
    for (int m = 0; m < 4; ++m)
#pragma unroll
      for (int n = 0; n < 4; ++n)
        acc[m][n] = __builtin_amdgcn_mfma_f32_16x16x32_f16(aX[m], b1[n], acc[m][n], 0, 0, 0);
    __builtin_amdgcn_s_setprio(0);
    __builtin_amdgcn_sched_barrier(0);

    // ---- phase 3: quadrant (mq=1, ks=1) ----
#pragma unroll
    for (int m = 0; m < 4; ++m)
      aY[m] = *(const f16x8*)&aB[((64 + m * 16 + ln)) * 64 + ko1];
    __builtin_amdgcn_s_setprio(1);
#pragma unroll
    for (int m = 0; m < 4; ++m)
#pragma unroll
      for (int n = 0; n < 4; ++n)
        acc[4 + m][n] = __builtin_amdgcn_mfma_f32_16x16x32_f16(aY[m], b1[n], acc[4 + m][n], 0, 0, 0);
    __builtin_amdgcn_s_setprio(0);

    // tile boundary: all stages for t+1 must be in LDS before next phase-0 reads
    if (pf) { VMCNT(0); }
    BARRIER();
  }

  // epilogue: tile row/col max -> LDS atomics -> global atomics
  __syncthreads();
  unsigned* red = (unsigned*)lbuf;   // [0..255]=row max, [256..511]=col max
  red[tid] = 0u;
  __syncthreads();

#pragma unroll
  for (int m = 0; m < 8; ++m) {
#pragma unroll
    for (int r2 = 0; r2 < 4; ++r2) {
      float v = fmaxf(fmaxf(acc[m][0][r2], acc[m][1][r2]),
                      fmaxf(acc[m][2][r2], acc[m][3][r2]));
#pragma unroll
      for (int s = 1; s < 16; s <<= 1) v = fmaxf(v, __shfl_xor(v, s));
      if (ln == 0) atomicMax(&red[wm * 128 + m * 16 + kq * 4 + r2], enc_f(v));
    }
  }
#pragma unroll
  for (int n = 0; n < 4; ++n) {
    float v = -3.4e38f;
#pragma unroll
    for (int m = 0; m < 8; ++m)
#pragma unroll
      for (int r2 = 0; r2 < 4; ++r2) v = fmaxf(v, acc[m][n][r2]);
    v = fmaxf(v, __shfl_xor(v, 16));
    v = fmaxf(v, __shfl_xor(v, 32));
    if (kq == 0) atomicMax(&red[256 + wn * 64 + n * 16 + ln], enc_f(v));
  }
  __syncthreads();
  if (tid < 256) atomicMax(&rmxg[(size_t)z * L_ + bx * 256 + tid], red[tid]);
  else           atomicMax(&cmxg[(size_t)z * L_ + by * 256 + (tid - 256)], red[tid]);
#undef STAGE_H
}

// ---------- softmax over 2048 encoded maxima per batch ----------
__global__ void softmax_k(const unsigned* __restrict__ enc, float* __restrict__ w) {
  __shared__ float red[256];
  const int b = blockIdx.x, tid = threadIdx.x;
  const unsigned* e = enc + (size_t)b * L_;
  float* wb = w + (size_t)b * L_;
  float vals[8];
  float lmax = -3.4e38f;
#pragma unroll
  for (int q = 0; q < 8; ++q) {
    float f = dec_f(e[q * 256 + tid]);
    vals[q] = f;
    lmax = fmaxf(lmax, f);
  }
  red[tid] = lmax; __syncthreads();
  for (int s = 128; s > 0; s >>= 1) {
    if (tid < s) red[tid] = fmaxf(red[tid], red[tid + s]);
    __syncthreads();
  }
  const float mx = red[0];
  __syncthreads();
  float lsum = 0.f;
#pragma unroll
  for (int q = 0; q < 8; ++q) { vals[q] = expf(vals[q] - mx); lsum += vals[q]; }
  red[tid] = lsum; __syncthreads();
  for (int s = 128; s > 0; s >>= 1) {
    if (tid < s) red[tid] += red[tid + s];
    __syncthreads();
  }
  const float inv = 1.f / red[0];
#pragma unroll
  for (int q = 0; q < 8; ++q) wb[q * 256 + tid] = vals[q] * inv;
}

// ---------- weighted sum (f16 input planes) ----------
__global__ void wsum_k(const float* __restrict__ w, const ushort* __restrict__ xh,
                       float* __restrict__ out) {
  __shared__ float ws[256];
  const int tid = threadIdx.x;
  const int b = blockIdx.y;
  const int i0 = blockIdx.x * 256;
  ws[tid] = w[(size_t)b * L_ + i0 + tid];
  __syncthreads();
  const int d0 = tid * 4;
  const ushort* xb = xh + ((size_t)b * L_ + i0) * D_ + d0;
  float4 acc = {0.f, 0.f, 0.f, 0.f};
  for (int i = 0; i < 256; ++i) {
    ushort4 v = *(const ushort4*)(xb + (size_t)i * D_);
    float wi = ws[i];
    acc.x = fmaf(wi, (float)__builtin_bit_cast(_Float16, v.x), acc.x);
    acc.y = fmaf(wi, (float)__builtin_bit_cast(_Float16, v.y), acc.y);
    acc.z = fmaf(wi, (float)__builtin_bit_cast(_Float16, v.z), acc.z);
    acc.w = fmaf(wi, (float)__builtin_bit_cast(_Float16, v.w), acc.w);
  }
  float* o = out + (size_t)b * D_ + d0;
  atomicAdd(o + 0, acc.x);
  atomicAdd(o + 1, acc.y);
  atomicAdd(o + 2, acc.z);
  atomicAdd(o + 3, acc.w);
}

extern "C" void kernel_launch(void* const* d_in, const int* in_sizes, int n_in,
                              void* d_out, int out_size, void* d_ws, size_t ws_size,
                              hipStream_t stream) {
  (void)in_sizes; (void)n_in; (void)out_size;
  const float* x1 = (const float*)d_in[0];
  const float* x2 = (const float*)d_in[1];
  const float* U  = (const float*)d_in[2];
  float* out = (float*)d_out;

  // workspace layout
  char* p = (char*)d_ws;
  ushort* UTh = (ushort*)p; p += (size_t)D_ * D_ * 2;
  ushort* UTl = (ushort*)p; p += (size_t)D_ * D_ * 2;
  unsigned* rowmax = (unsigned*)p; p += (size_t)B_ * L_ * 4;
  unsigned* colmax = (unsigned*)p; p += (size_t)B_ * L_ * 4;
  float* w1 = (float*)p; p += (size_t)B_ * L_ * 4;
  float* w2 = (float*)p; p += (size_t)B_ * L_ * 4;
  const size_t fixed = (size_t)(p - (char*)d_ws);
  const size_t perB = (size_t)3 * L_ * D_ * 2;    // 3 f16 planes per batch = 12MB
  int G = 1;
  if (ws_size > fixed) {
    size_t g = (ws_size - fixed) / perB;
    G = g < 1 ? 1 : (g > (size_t)B_ ? B_ : (int)g);
  }
  ushort* x1h = (ushort*)p;
  ushort* x2h = x1h + (size_t)G * L_ * D_;
  ushort* Yh  = x2h + (size_t)G * L_ * D_;

  hipMemsetAsync(d_out, 0, (size_t)2 * B_ * D_ * 4, stream);
  hipMemsetAsync(rowmax, 0, (size_t)2 * B_ * L_ * 4, stream); // rowmax+colmax contiguous

  transdec_k<<<dim3(32, 32), dim3(32, 8), 0, stream>>>(U, UTh, UTl);

  for (int g0 = 0; g0 < B_; g0 += G) {
    const int Gc = (B_ - g0) < G ? (B_ - g0) : G;
    const int n4 = Gc * (L_ * D_ / 4);
    dec1_k<<<dim3(1024), 256, 0, stream>>>(
        (const float4*)(x1 + (size_t)g0 * L_ * D_), (uint2*)x1h, n4);
    dec1_k<<<dim3(1024), 256, 0, stream>>>(
        (const float4*)(x2 + (size_t)g0 * L_ * D_), (uint2*)x2h, n4);
    gemm1_k<<<dim3(32, 1, Gc), 512, 0, stream>>>(x1h, UTh, UTl, Yh);
    gemm2_k<<<dim3(64, 1, Gc), 512, 0, stream>>>(Yh, x2h,
        rowmax + (size_t)g0 * L_, colmax + (size_t)g0 * L_);
    // per-group softmax + weighted sums (f16 planes are group-local)
    softmax_k<<<dim3(Gc), 256, 0, stream>>>(rowmax + (size_t)g0 * L_,
                                            w1 + (size_t)g0 * L_);
    softmax_k<<<dim3(Gc), 256, 0, stream>>>(colmax + (size_t)g0 * L_,
                                            w2 + (size_t)g0 * L_);
    wsum_k<<<dim3(8, Gc), 256, 0, stream>>>(w1 + (size_t)g0 * L_, x1h,
                                            out + (size_t)g0 * D_);
    wsum_k<<<dim3(8, Gc), 256, 0, stream>>>(w2 + (size_t)g0 * L_, x2h,
                                            out + (size_t)(B_ + g0) * D_);
  }
}

// Round 15
// 713.843 us; speedup vs baseline: 1.6599x; 1.0093x over previous
//
#include <hip/hip_runtime.h>
#include <hip/hip_bf16.h>
#include <stdint.h>

#define B_  32
#define L_  2048   // L1 == L2
#define D_  1024   // D1 == D2

typedef __attribute__((ext_vector_type(8))) _Float16 f16x8;
typedef __attribute__((ext_vector_type(4))) float f32x4;

// ---------- helpers ----------
__device__ __forceinline__ unsigned enc_f(float x) {
  unsigned u = __float_as_uint(x);
  return (u & 0x80000000u) ? ~u : (u | 0x80000000u);
}
__device__ __forceinline__ float dec_f(unsigned e) {
  unsigned u = (e & 0x80000000u) ? (e ^ 0x80000000u) : ~e;
  return __uint_as_float(u);
}
__device__ __forceinline__ ushort f16_bits(float x) {
  _Float16 h = (_Float16)x;               // RNE convert
  return __builtin_bit_cast(ushort, h);
}
__device__ __forceinline__ void split_f16(float x, ushort& h, ushort& l) {
  _Float16 hf = (_Float16)x;
  float r = x - (float)hf;
  h = __builtin_bit_cast(ushort, hf);
  l = __builtin_bit_cast(ushort, (_Float16)r);
}

// async global->LDS, 16B per lane; LDS dest wave-uniform, lane*16 placement.
__device__ __forceinline__ void gl_lds16(const ushort* g, ushort* l) {
  using gas_t = const __attribute__((address_space(1))) uint32_t*;
  using las_t = __attribute__((address_space(3))) uint32_t*;
  __builtin_amdgcn_global_load_lds((gas_t)(uintptr_t)g,
                                   (las_t)(unsigned)(uintptr_t)l, 16, 0, 0);
}

// ---------- decompose fp32 -> f16 hi plane only ----------
__global__ void dec1_k(const float4* __restrict__ x, uint2* __restrict__ h, int n4) {
  int i = blockIdx.x * blockDim.x + threadIdx.x;
  const int stride = gridDim.x * blockDim.x;
  for (; i < n4; i += stride) {
    float4 v = x[i];
    uint2 hw;
    hw.x = (unsigned)f16_bits(v.x) | ((unsigned)f16_bits(v.y) << 16);
    hw.y = (unsigned)f16_bits(v.z) | ((unsigned)f16_bits(v.w) << 16);
    h[i] = hw;
  }
}

// ---------- transpose + decompose U (scaled by 2048 to keep U_lo in f16 normal range) ----------
__global__ void transdec_k(const float* __restrict__ U,
                           ushort* __restrict__ UTh, ushort* __restrict__ UTl) {
  __shared__ float t[32][33];
  const int tx = threadIdx.x, ty = threadIdx.y;
  const int e0 = blockIdx.x * 32, d0 = blockIdx.y * 32;
#pragma unroll
  for (int r = 0; r < 4; ++r)
    t[ty + r * 8][tx] = U[(size_t)(d0 + ty + r * 8) * D_ + e0 + tx];
  __syncthreads();
#pragma unroll
  for (int r = 0; r < 4; ++r) {
    int e = ty + r * 8;
    ushort h, l;
    split_f16(t[tx][e] * 2048.0f, h, l);
    UTh[(size_t)(e0 + e) * D_ + d0 + tx] = h;
    UTl[(size_t)(e0 + e) * D_ + d0 + tx] = l;
  }
}

// ============ 256x256 tile GEMM cores: 8 waves (2x4), f16 ============
struct CoreCtx {
  int w, lane, ln, kq, wm, wn, ko;
  size_t soA;   // BK=32 staging offset (gemm1)
};

__device__ __forceinline__ CoreCtx make_ctx() {
  CoreCtx c;
  const int tid = threadIdx.x;
  c.w = tid >> 6; c.lane = tid & 63;
  c.ln = c.lane & 15; c.kq = c.lane >> 4;
  c.wm = c.w >> 2; c.wn = c.w & 3;
  c.ko = (c.kq ^ ((c.ln >> 1) & 3)) * 8;
  const int srow = c.lane >> 2;
  const int sslot = (c.lane & 3) ^ ((c.lane >> 3) & 3);
  c.soA = (size_t)(c.w * 32 + srow) * D_ + sslot * 8;
  return c;
}

// stage one 256x32 plane (BK=32): wave w covers rows [w*32, w*32+32), 2 gl_lds
__device__ __forceinline__ void stage_plane(const ushort* src, ushort* dstbase,
                                            const CoreCtx& c, int k0) {
  const size_t a0 = c.soA + k0, a1 = a0 + (size_t)16 * D_;
  ushort* d0 = dstbase + c.w * 1024;
  gl_lds16(src + a0, d0);
  gl_lds16(src + a1, d0 + 512);
}

#define VMCNT(n) asm volatile("s_waitcnt vmcnt(" #n ")" ::: "memory")
#define BARRIER() do { asm volatile("" ::: "memory"); \
                       __builtin_amdgcn_s_barrier();  \
                       asm volatile("" ::: "memory"); } while (0)

// --- gemm1 core: 3 planes (Ah | Bh | Bl), BK=32, 2-phase counted-vmcnt (r8-proven) ---
__device__ __forceinline__ void core_loop3(const CoreCtx& c,
    const ushort* Ah, const ushort* Bh, const ushort* Bl,
    ushort* lbuf, f32x4 acc[8][4])
{
  stage_plane(Ah, lbuf,         c, 0);
  stage_plane(Bh, lbuf + 8192,  c, 0);
  stage_plane(Bl, lbuf + 16384, c, 0);

  for (int t = 0; t < 32; ++t) {
    const ushort* cb = lbuf + (t & 1) * 24576;
    ushort* nb = lbuf + ((t + 1) & 1) * 24576;
    const int kn = (t + 1) * 32;
    const bool pf = (t < 31);
    f16x8 a[8], bh4[4], bl4[4];

    // ---- phase 1: hh ----
    VMCNT(2);                       // Ah,Bh(t) landed; Bl(t) may fly
    BARRIER();
#pragma unroll
    for (int n = 0; n < 4; ++n) {
      const int r = c.wn * 64 + n * 16 + c.ln;
      bh4[n] = *(const f16x8*)&cb[8192 + r * 32 + c.ko];
    }
#pragma unroll
    for (int m = 0; m < 8; ++m) {
      const int r = c.wm * 128 + m * 16 + c.ln;
      a[m] = *(const f16x8*)&cb[r * 32 + c.ko];
    }
    if (pf) { stage_plane(Ah, nb, c, kn); stage_plane(Bh, nb + 8192, c, kn); }
    __builtin_amdgcn_s_setprio(1);
#pragma unroll
    for (int m = 0; m < 8; ++m)
#pragma unroll
      for (int n = 0; n < 4; ++n)
        acc[m][n] = __builtin_amdgcn_mfma_f32_16x16x32_f16(a[m], bh4[n], acc[m][n], 0, 0, 0);
    __builtin_amdgcn_s_setprio(0);

    // ---- phase 2: A_hi x B_lo ----
    if (pf) { VMCNT(4); } else { VMCNT(0); }   // Bl(t) landed
    BARRIER();
#pragma unroll
    for (int n = 0; n < 4; ++n) {
      const int r = c.wn * 64 + n * 16 + c.ln;
      bl4[n] = *(const f16x8*)&cb[16384 + r * 32 + c.ko];
    }
    if (pf) stage_plane(Bl, nb + 16384, c, kn);
    __builtin_amdgcn_s_setprio(1);
#pragma unroll
    for (int m = 0; m < 8; ++m)
#pragma unroll
      for (int n = 0; n < 4; ++n)
        acc[m][n] = __builtin_amdgcn_mfma_f32_16x16x32_f16(a[m], bl4[n], acc[m][n], 0, 0, 0);
    __builtin_amdgcn_s_setprio(0);
  }
}

// ---------- GEMM1: Y = (x1 @ (U*2048)) / 2048 -> f16 hi plane ----------
__global__ __launch_bounds__(512, 2) void gemm1_k(
    const ushort* __restrict__ x1h,
    const ushort* __restrict__ UTh, const ushort* __restrict__ UTl,
    ushort* __restrict__ Yh)
{
  __shared__ __attribute__((aligned(16))) ushort lbuf[65536];
  const int z = blockIdx.z;
  const int orig = blockIdx.x;                 // 0..31
  const int xc = orig & 7, j = orig >> 3;      // j 0..3
  const int bx = (xc & 3) * 2 + (j & 1);       // 0..7
  const int by = (xc >> 2) * 2 + (j >> 1);     // 0..3

  const size_t zb = (size_t)z * (L_ * D_);
  const ushort* Ah = x1h + zb + (size_t)bx * 256 * D_;
  const ushort* Bh = UTh + (size_t)by * 256 * D_;
  const ushort* Bl = UTl + (size_t)by * 256 * D_;

  CoreCtx c = make_ctx();
  f32x4 acc[8][4];
#pragma unroll
  for (int m = 0; m < 8; ++m)
#pragma unroll
    for (int n = 0; n < 4; ++n) acc[m][n] = (f32x4){0.f, 0.f, 0.f, 0.f};

  core_loop3(c, Ah, Bh, Bl, lbuf, acc);

  __syncthreads();   // lbuf reused below

  // epilogue: unscale by 2^-11, convert to f16, LDS-coalesce, write Yh.
  ushort* ep = lbuf + c.w * 8192;
  const int grow = bx * 256 + c.wm * 128;
  const int gcol = by * 256 + c.wn * 64;
#pragma unroll
  for (int m = 0; m < 8; ++m)
#pragma unroll
    for (int n = 0; n < 4; ++n)
#pragma unroll
      for (int r2 = 0; r2 < 4; ++r2) {
        float v = acc[m][n][r2] * 4.8828125e-4f;   // 1/2048
        ep[(m * 16 + c.kq * 4 + r2) * 64 + n * 16 + c.ln] = f16_bits(v);
      }
#pragma unroll
  for (int q = 0; q < 16; ++q) {
    const int chunk = q * 64 + c.lane;
    const int row = chunk >> 3, c8 = (chunk & 7) * 8;
    f16x8 v = *(const f16x8*)&ep[row * 64 + c8];
    *(f16x8*)&Yh[zb + (size_t)(grow + row) * D_ + gcol + c8] = v;
  }
}

// ---------- GEMM2: M = Yh @ x2h^T, BK=64, faithful m201 4-phase template ----------
// LDS: 2 buffers x (A[256][64] | B[256][64]) = 128KB. Rows of 64 ushorts =
// 8 x 16B slots; swizzle phys_slot = slot ^ (row&7), applied on the GLOBAL
// source at stage time and on the ds_read address (r11/r13-verified).
//
// Per tile t, 4 phases; each phase:
//   { ds_read frags | issue 1 half-tile stage (2 gl_lds) | counted vmcnt |
//     barrier | setprio(1) 16 MFMA setprio(0) | barrier }
// Stage order (tile t stages tile t+1): ph0->A0', ph1->B0', ph2->B1', ph3->A1'.
// Consumption (tile t): ph0 reads A0,B0; ph1 reads B1; ph2 reads A1; ph3 none.
// vmcnt(4) at ph0/ph1/ph3; >=4 loads always in flight mid-loop (T4).
__global__ __launch_bounds__(512, 2) void gemm2_k(
    const ushort* __restrict__ Yh,
    const ushort* __restrict__ x2h,
    unsigned* __restrict__ rmxg, unsigned* __restrict__ cmxg)
{
  __shared__ __attribute__((aligned(16))) ushort lbuf[65536];  // 2 x 32768
  const int z = blockIdx.z;
  const int orig = blockIdx.x;                 // 0..63
  const int xc = orig & 7, j = orig >> 3;      // j 0..7
  const int bx = (xc & 3) * 2 + (j & 1);       // 0..7
  const int by = (xc >> 2) * 4 + (j >> 1);     // 0..7

  const size_t zb = (size_t)z * (L_ * D_);
  const ushort* Ap = Yh + zb + (size_t)bx * 256 * D_;
  const ushort* Bp = x2h + zb + (size_t)by * 256 * D_;

  const int tid = threadIdx.x;
  const int w = tid >> 6, lane = tid & 63;
  const int ln = lane & 15, kq = lane >> 4;
  const int wm = w >> 2, wn = w & 3;
  const int ko0 = ((kq)     ^ (ln & 7)) * 8;   // ks=0 slot (swizzled), ushorts
  const int ko1 = ((4 + kq) ^ (ln & 7)) * 8;   // ks=1
  const int srh = lane >> 3;                   // 0..7
  const int ssl = (lane & 7) ^ srh;            // swizzled source slot
  const int rA0 = (w >> 2) * 128 + (w & 3) * 16;  // per-wave A row base (stage)
  const int rB0 = (w >> 1) * 64 + (w & 1) * 16;   // per-wave B row base (stage)

  f32x4 acc[8][4];
#pragma unroll
  for (int m = 0; m < 8; ++m)
#pragma unroll
    for (int n = 0; n < 4; ++n) acc[m][n] = (f32x4){0.f, 0.f, 0.f, 0.f};

// kt = TILE INDEX (k element offset = kt*64)
#define STG(nbuf, plofs, srcp, rowbase, kt) do {                                     \
    const size_t a_ = (size_t)((rowbase) + srh) * D_ + (size_t)(kt) * 64 + ssl * 8;  \
    ushort* d_ = (nbuf) + (plofs) + (rowbase) * 64;                                  \
    gl_lds16((srcp) + a_, d_);                                                       \
    gl_lds16((srcp) + a_ + (size_t)8 * D_, d_ + 512);                                \
  } while (0)

  // prologue: tile 0's 4 halves in consumption order A0,B0,B1,A1
  STG(lbuf, 0,     Ap, rA0,      0);
  STG(lbuf, 16384, Bp, rB0,      0);
  STG(lbuf, 16384, Bp, rB0 + 32, 0);
  STG(lbuf, 0,     Ap, rA0 + 64, 0);
  VMCNT(4);            // A0(0),B0(0) landed; B1(0),A1(0) in flight
  BARRIER();

  f16x8 a[4][2], b0[2][2], b1[2][2];

  for (int t = 0; t < 16; ++t) {
    const ushort* cb = lbuf + (t & 1) * 32768;
    ushort* nb = lbuf + ((t + 1) & 1) * 32768;
    const bool pf = (t < 15);
    const int kn = t + 1;                      // FIXED: tile index, not element offset
    const ushort* aP = cb;
    const ushort* bP = cb + 16384;

    // ===== phase 0: m0-3 x n0-1 (reads A-half0 + B-half0) =====
#pragma unroll
    for (int ks = 0; ks < 2; ++ks) {
      const int ko = ks ? ko1 : ko0;
#pragma unroll
      for (int nt = 0; nt < 2; ++nt)
        b0[nt][ks] = *(const f16x8*)&bP[(wn * 64 + nt * 16 + ln) * 64 + ko];
#pragma unroll
      for (int m = 0; m < 4; ++m)
        a[m][ks] = *(const f16x8*)&aP[(wm * 128 + m * 16 + ln) * 64 + ko];
    }
    if (pf) STG(nb, 0, Ap, rA0, kn);
    if (pf) { VMCNT(4); } else { VMCNT(2); }   // publish B1(t)
    BARRIER();
    __builtin_amdgcn_s_setprio(1);
#pragma unroll
    for (int ks = 0; ks < 2; ++ks)
#pragma unroll
      for (int m = 0; m < 4; ++m)
#pragma unroll
        for (int nt = 0; nt < 2; ++nt)
          acc[m][nt] = __builtin_amdgcn_mfma_f32_16x16x32_f16(a[m][ks], b0[nt][ks], acc[m][nt], 0, 0, 0);
    __builtin_amdgcn_s_setprio(0);
    BARRIER();

    // ===== phase 1: m0-3 x n2-3 (reads B-half1) =====
#pragma unroll
    for (int ks = 0; ks < 2; ++ks) {
      const int ko = ks ? ko1 : ko0;
#pragma unroll
      for (int nt = 0; nt < 2; ++nt)
        b1[nt][ks] = *(const f16x8*)&bP[(wn * 64 + (2 + nt) * 16 + ln) * 64 + ko];
    }
    if (pf) STG(nb, 16384, Bp, rB0, kn);
    if (pf) { VMCNT(4); } else { VMCNT(0); }   // publish A1(t)
    BARRIER();
    __builtin_amdgcn_s_setprio(1);
#pragma unroll
    for (int ks = 0; ks < 2; ++ks)
#pragma unroll
      for (int m = 0; m < 4; ++m)
#pragma unroll
        for (int nt = 0; nt < 2; ++nt)
          acc[m][2 + nt] = __builtin_amdgcn_mfma_f32_16x16x32_f16(a[m][ks], b1[nt][ks], acc[m][2 + nt], 0, 0, 0);
    __builtin_amdgcn_s_setprio(0);
    BARRIER();

    // ===== phase 2: m4-7 x n0-1 (reads A-half1; overwrites a[][]) =====
#pragma unroll
    for (int ks = 0; ks < 2; ++ks) {
      const int ko = ks ? ko1 : ko0;
#pragma unroll
      for (int m = 0; m < 4; ++m)
        a[m][ks] = *(const f16x8*)&aP[(wm * 128 + (4 + m) * 16 + ln) * 64 + ko];
    }
    if (pf) STG(nb, 16384, Bp, rB0 + 32, kn);
    BARRIER();                                  // no vmcnt: ph3 reads nothing
    __builtin_amdgcn_s_setprio(1);
#pragma unroll
    for (int ks = 0; ks < 2; ++ks)
#pragma unroll
      for (int m = 0; m < 4; ++m)
#pragma unroll
        for (int nt = 0; nt < 2; ++nt)
          acc[4 + m][nt] = __builtin_amdgcn_mfma_f32_16x16x32_f16(a[m][ks], b0[nt][ks], acc[4 + m][nt], 0, 0, 0);
    __builtin_amdgcn_s_setprio(0);
    BARRIER();

    // ===== phase 3: m4-7 x n2-3 (no reads) =====
    if (pf) STG(nb, 0, Ap, rA0 + 64, kn);
    if (pf) { VMCNT(4); }                       // publish A0(t+1),B0(t+1)
    BARRIER();
    __builtin_amdgcn_s_setprio(1);
#pragma unroll
    for (int ks = 0; ks < 2; ++ks)
#pragma unroll
      for (int m = 0; m < 4; ++m)
#pragma unroll
        for (int nt = 0; nt < 2; ++nt)
          acc[4 + m][2 + nt] = __builtin_amdgcn_mfma_f32_16x16x32_f16(a[m][ks], b1[nt][ks], acc[4 + m][2 + nt], 0, 0, 0);
    __builtin_amdgcn_s_setprio(0);
    BARRIER();
  }
#undef STG

  // epilogue: tile row/col max -> LDS atomics -> global atomics
  __syncthreads();
  unsigned* red = (unsigned*)lbuf;   // [0..255]=row max, [256..511]=col max
  red[tid] = 0u;
  __syncthreads();

#pragma unroll
  for (int m = 0; m < 8; ++m) {
#pragma unroll
    for (int r2 = 0; r2 < 4; ++r2) {
      float v = fmaxf(fmaxf(acc[m][0][r2], acc[m][1][r2]),
                      fmaxf(acc[m][2][r2], acc[m][3][r2]));
#pragma unroll
      for (int s = 1; s < 16; s <<= 1) v = fmaxf(v, __shfl_xor(v, s));
      if (ln == 0) atomicMax(&red[wm * 128 + m * 16 + kq * 4 + r2], enc_f(v));
    }
  }
#pragma unroll
  for (int n = 0; n < 4; ++n) {
    float v = -3.4e38f;
#pragma unroll
    for (int m = 0; m < 8; ++m)
#pragma unroll
      for (int r2 = 0; r2 < 4; ++r2) v = fmaxf(v, acc[m][n][r2]);
    v = fmaxf(v, __shfl_xor(v, 16));
    v = fmaxf(v, __shfl_xor(v, 32));
    if (kq == 0) atomicMax(&red[256 + wn * 64 + n * 16 + ln], enc_f(v));
  }
  __syncthreads();
  if (tid < 256) atomicMax(&rmxg[(size_t)z * L_ + bx * 256 + tid], red[tid]);
  else           atomicMax(&cmxg[(size_t)z * L_ + by * 256 + (tid - 256)], red[tid]);
}

// ---------- softmax over 2048 encoded maxima per batch ----------
__global__ void softmax_k(const unsigned* __restrict__ enc, float* __restrict__ w) {
  __shared__ float red[256];
  const int b = blockIdx.x, tid = threadIdx.x;
  const unsigned* e = enc + (size_t)b * L_;
  float* wb = w + (size_t)b * L_;
  float vals[8];
  float lmax = -3.4e38f;
#pragma unroll
  for (int q = 0; q < 8; ++q) {
    float f = dec_f(e[q * 256 + tid]);
    vals[q] = f;
    lmax = fmaxf(lmax, f);
  }
  red[tid] = lmax; __syncthreads();
  for (int s = 128; s > 0; s >>= 1) {
    if (tid < s) red[tid] = fmaxf(red[tid], red[tid + s]);
    __syncthreads();
  }
  const float mx = red[0];
  __syncthreads();
  float lsum = 0.f;
#pragma unroll
  for (int q = 0; q < 8; ++q) { vals[q] = expf(vals[q] - mx); lsum += vals[q]; }
  red[tid] = lsum; __syncthreads();
  for (int s = 128; s > 0; s >>= 1) {
    if (tid < s) red[tid] += red[tid + s];
    __syncthreads();
  }
  const float inv = 1.f / red[0];
#pragma unroll
  for (int q = 0; q < 8; ++q) wb[q * 256 + tid] = vals[q] * inv;
}

// ---------- weighted sum (f16 input planes) ----------
__global__ void wsum_k(const float* __restrict__ w, const ushort* __restrict__ xh,
                       float* __restrict__ out) {
  __shared__ float ws[256];
  const int tid = threadIdx.x;
  const int b = blockIdx.y;
  const int i0 = blockIdx.x * 256;
  ws[tid] = w[(size_t)b * L_ + i0 + tid];
  __syncthreads();
  const int d0 = tid * 4;
  const ushort* xb = xh + ((size_t)b * L_ + i0) * D_ + d0;
  float4 acc = {0.f, 0.f, 0.f, 0.f};
  for (int i = 0; i < 256; ++i) {
    ushort4 v = *(const ushort4*)(xb + (size_t)i * D_);
    float wi = ws[i];
    acc.x = fmaf(wi, (float)__builtin_bit_cast(_Float16, v.x), acc.x);
    acc.y = fmaf(wi, (float)__builtin_bit_cast(_Float16, v.y), acc.y);
    acc.z = fmaf(wi, (float)__builtin_bit_cast(_Float16, v.z), acc.z);
    acc.w = fmaf(wi, (float)__builtin_bit_cast(_Float16, v.w), acc.w);
  }
  float* o = out + (size_t)b * D_ + d0;
  atomicAdd(o + 0, acc.x);
  atomicAdd(o + 1, acc.y);
  atomicAdd(o + 2, acc.z);
  atomicAdd(o + 3, acc.w);
}

extern "C" void kernel_launch(void* const* d_in, const int* in_sizes, int n_in,
                              void* d_out, int out_size, void* d_ws, size_t ws_size,
                              hipStream_t stream) {
  (void)in_sizes; (void)n_in; (void)out_size;
  const float* x1 = (const float*)d_in[0];
  const float* x2 = (const float*)d_in[1];
  const float* U  = (const float*)d_in[2];
  float* out = (float*)d_out;

  // workspace layout
  char* p = (char*)d_ws;
  ushort* UTh = (ushort*)p; p += (size_t)D_ * D_ * 2;
  ushort* UTl = (ushort*)p; p += (size_t)D_ * D_ * 2;
  unsigned* rowmax = (unsigned*)p; p += (size_t)B_ * L_ * 4;
  unsigned* colmax = (unsigned*)p; p += (size_t)B_ * L_ * 4;
  float* w1 = (float*)p; p += (size_t)B_ * L_ * 4;
  float* w2 = (float*)p; p += (size_t)B_ * L_ * 4;
  const size_t fixed = (size_t)(p - (char*)d_ws);
  const size_t perB = (size_t)3 * L_ * D_ * 2;    // 3 f16 planes per batch = 12MB
  int G = 1;
  if (ws_size > fixed) {
    size_t g = (ws_size - fixed) / perB;
    G = g < 1 ? 1 : (g > (size_t)B_ ? B_ : (int)g);
  }
  ushort* x1h = (ushort*)p;
  ushort* x2h = x1h + (size_t)G * L_ * D_;
  ushort* Yh  = x2h + (size_t)G * L_ * D_;

  hipMemsetAsync(d_out, 0, (size_t)2 * B_ * D_ * 4, stream);
  hipMemsetAsync(rowmax, 0, (size_t)2 * B_ * L_ * 4, stream); // rowmax+colmax contiguous

  transdec_k<<<dim3(32, 32), dim3(32, 8), 0, stream>>>(U, UTh, UTl);

  for (int g0 = 0; g0 < B_; g0 += G) {
    const int Gc = (B_ - g0) < G ? (B_ - g0) : G;
    const int n4 = Gc * (L_ * D_ / 4);
    dec1_k<<<dim3(1024), 256, 0, stream>>>(
        (const float4*)(x1 + (size_t)g0 * L_ * D_), (uint2*)x1h, n4);
    dec1_k<<<dim3(1024), 256, 0, stream>>>(
        (const float4*)(x2 + (size_t)g0 * L_ * D_), (uint2*)x2h, n4);
    gemm1_k<<<dim3(32, 1, Gc), 512, 0, stream>>>(x1h, UTh, UTl, Yh);
    gemm2_k<<<dim3(64, 1, Gc), 512, 0, stream>>>(Yh, x2h,
        rowmax + (size_t)g0 * L_, colmax + (size_t)g0 * L_);
    // per-group softmax + weighted sums (f16 planes are group-local)
    softmax_k<<<dim3(Gc), 256, 0, stream>>>(rowmax + (size_t)g0 * L_,
                                            w1 + (size_t)g0 * L_);
    softmax_k<<<dim3(Gc), 256, 0, stream>>>(colmax + (size_t)g0 * L_,
                                            w2 + (size_t)g0 * L_);
    wsum_k<<<dim3(8, Gc), 256, 0, stream>>>(w1 + (size_t)g0 * L_, x1h,
                                            out + (size_t)g0 * D_);
    wsum_k<<<dim3(8, Gc), 256, 0, stream>>>(w2 + (size_t)g0 * L_, x2h,
                                            out + (size_t)(B_ + g0) * D_);
  }
}